// Round 1
// baseline (5065.572 us; speedup 1.0000x reference)
//
#include <hip/hip_runtime.h>
#include <hip/hip_bf16.h>
#include <math.h>

#define B_ 8
#define C_ 256
#define H_ 64
#define W_ 64
#define P_ 4096   /* H*W */

// ---------------------------------------------------------------------------
// LayerNorm over channel axis: per (b,p) reduce over C channels (stride P_).
// Safe when in == out (each thread only touches its own (b,p) column).
// ---------------------------------------------------------------------------
__global__ __launch_bounds__(256)
void ln_ch_kernel(const float* __restrict__ in, float* __restrict__ out,
                  const float* __restrict__ gw, const float* __restrict__ gb,
                  int C)
{
    int g = blockIdx.x * 256 + threadIdx.x;     // b*P_ + p, total B_*P_
    int b = g >> 12;
    int p = g & 4095;
    size_t base = (size_t)b * C * P_ + p;
    float s = 0.f, s2 = 0.f;
    for (int c = 0; c < C; ++c) {
        float x = in[base + (size_t)c * P_];
        s += x; s2 += x * x;
    }
    float mu  = s / C;
    float var = s2 / C - mu * mu;
    float inv = 1.0f / sqrtf(var + 1e-5f);
    for (int c = 0; c < C; ++c) {
        float x = in[base + (size_t)c * P_];
        out[base + (size_t)c * P_] = (x - mu) * inv * gw[c] + gb[c];
    }
}

// ---------------------------------------------------------------------------
// q_shift + saliency blend: x_sh = mask*shift(xn) + (1-mask)*xn
// quadrants of C: 0:w-1, 1:w+1, 2:h-1, 3:h+1 (zero pad at borders)
// ---------------------------------------------------------------------------
__global__ __launch_bounds__(256)
void qshift_kernel(const float* __restrict__ xn, const float* __restrict__ mask,
                   float* __restrict__ xsh)
{
    int g = blockIdx.x * 256 + threadIdx.x;     // B_*C_*P_ total
    int p = g & 4095;
    int c = (g >> 12) & 255;
    int b = g >> 20;
    int h = p >> 6, w = p & 63;
    float xs = 0.f;
    int quad = c >> 6;
    if (quad == 0)      { if (w > 0)  xs = xn[g - 1];  }
    else if (quad == 1) { if (w < 63) xs = xn[g + 1];  }
    else if (quad == 2) { if (h > 0)  xs = xn[g - 64]; }
    else                { if (h < 63) xs = xn[g + 64]; }
    float m = mask[(b << 12) + p];
    xsh[g] = m * xs + (1.f - m) * xn[g];
}

// ---------------------------------------------------------------------------
// Generic 1x1-conv GEMM: out[b,o,p] = sum_k W[o,k] * Xeff[b,k,p]  (+ epilogue)
//   INM: 0 plain Xeff=X; 1 mix Xeff=mix[k]*X+(1-mix[k])*X2; 2 mul Xeff=X*X2
//   EPI: 0 none; 1 sigmoid; 2 +bias; 3 +res[b,o,p]; 4 gelu(x+bias)*bn; 5 pixel-shuffle
// 64x64 tile, BK=16, 256 threads, 4x4 per thread.
// ---------------------------------------------------------------------------
#define IN_PLAIN 0
#define IN_MIX   1
#define IN_MUL   2
#define EP_NONE    0
#define EP_SIGMOID 1
#define EP_BIAS    2
#define EP_RES     3
#define EP_GELU_BN 4
#define EP_SHUFFLE 5

template<int INM, int EPI>
__global__ __launch_bounds__(256)
void gemm1x1_kernel(const float* __restrict__ Wm,   // O x K
                    const float* __restrict__ X,    // B x K x P_
                    const float* __restrict__ X2,   // B x K x P_ (mix/mul)
                    const float* __restrict__ mixv, // [K]
                    const float* __restrict__ bias, // [O]
                    const float* __restrict__ bng,  // [O]
                    const float* __restrict__ bnb,  // [O]
                    const float* __restrict__ res,  // B x 256 x P_
                    float* __restrict__ Out,
                    int O, int K, int obs, int ocoff)
{
    __shared__ float Ws[16][68];
    __shared__ float Xs[16][64];
    int tid = threadIdx.x;
    int p0 = blockIdx.x * 64;
    int o0 = blockIdx.y * 64;
    int b  = blockIdx.z;
    const float* Xb  = X + (size_t)b * K * P_;
    const float* X2b = (INM != IN_PLAIN) ? (X2 + (size_t)b * K * P_) : nullptr;

    int tx = tid & 15, ty = tid >> 4;
    int wo  = tid >> 2;          // o row for W staging (0..63)
    int wc4 = (tid & 3) * 4;     // k offset for W staging
    int xp  = tid & 63;          // p for X staging
    int xc  = tid >> 6;          // base c for X staging (0..3)

    float acc[4][4] = {};

    for (int k0 = 0; k0 < K; k0 += 16) {
        float4 wv = *reinterpret_cast<const float4*>(&Wm[(size_t)(o0 + wo) * K + k0 + wc4]);
        Ws[wc4 + 0][wo] = wv.x; Ws[wc4 + 1][wo] = wv.y;
        Ws[wc4 + 2][wo] = wv.z; Ws[wc4 + 3][wo] = wv.w;
        #pragma unroll
        for (int j = 0; j < 4; ++j) {
            int c = xc + j * 4;
            size_t idx = (size_t)(k0 + c) * P_ + p0 + xp;
            float v;
            if (INM == IN_PLAIN)      v = Xb[idx];
            else if (INM == IN_MIX) { float m = mixv[k0 + c]; v = m * Xb[idx] + (1.f - m) * X2b[idx]; }
            else                      v = Xb[idx] * X2b[idx];
            Xs[c][xp] = v;
        }
        __syncthreads();
        #pragma unroll
        for (int kk = 0; kk < 16; ++kk) {
            float4 av = *reinterpret_cast<const float4*>(&Ws[kk][ty * 4]);
            float4 xv = *reinterpret_cast<const float4*>(&Xs[kk][tx * 4]);
            float aa[4] = {av.x, av.y, av.z, av.w};
            float xx[4] = {xv.x, xv.y, xv.z, xv.w};
            #pragma unroll
            for (int i = 0; i < 4; ++i)
                #pragma unroll
                for (int j = 0; j < 4; ++j)
                    acc[i][j] += aa[i] * xx[j];
        }
        __syncthreads();
    }

    #pragma unroll
    for (int i = 0; i < 4; ++i) {
        int o = o0 + ty * 4 + i;
        float bi = 0.f, sc = 0.f, sh = 0.f;
        if (EPI == EP_BIAS || EPI == EP_GELU_BN || EPI == EP_SHUFFLE) bi = bias[o];
        if (EPI == EP_GELU_BN) { sc = bng[o] * (1.0f / sqrtf(1.f + 1e-5f)); sh = bnb[o]; }
        #pragma unroll
        for (int j = 0; j < 4; ++j) {
            int p = p0 + tx * 4 + j;
            float t = acc[i][j];
            if (EPI == EP_SIGMOID) t = 1.f / (1.f + expf(-t));
            if (EPI == EP_BIAS)    t += bi;
            if (EPI == EP_RES)     t += res[((size_t)b * 256 + o) * P_ + p];
            if (EPI == EP_GELU_BN) {
                t += bi;
                t = 0.5f * t * (1.f + erff(t * 0.70710678118654752f));
                t = t * sc + sh;
            }
            if (EPI == EP_SHUFFLE) {
                t += bi;
                int co = o >> 2, s1 = (o >> 1) & 1, s2 = o & 1;
                int h = p >> 6, w = p & 63;
                Out[(((size_t)b * 128 + co) * 128 + h * 2 + s1) * 128 + w * 2 + s2] = t;
            } else {
                Out[((size_t)b * obs + ocoff + o) * P_ + p] = t;
            }
        }
    }
}

// ---------------------------------------------------------------------------
// Grouped 3x3 conv (groups=2) + bias + exact GELU + BN-eval.
// Block: 256 threads -> 32 output channels x 64 w positions at one (b,h).
// ---------------------------------------------------------------------------
__global__ __launch_bounds__(256)
void conv3x3_kernel(const float* __restrict__ xcat, const float* __restrict__ cw,
                    const float* __restrict__ cb, const float* __restrict__ bg,
                    const float* __restrict__ bb, float* __restrict__ y1)
{
    __shared__ float Xt[8][3][66];
    __shared__ float Wt[32][72];
    int h  = blockIdx.x;
    int o0 = blockIdx.y * 32;
    int b  = blockIdx.z;
    int tid = threadIdx.x;
    int group = o0 >> 8;
    int cbase = group << 8;
    int w  = tid & 63;
    int o4 = tid >> 6;           // 0..3
    float acc[8] = {};

    for (int c0 = 0; c0 < 256; c0 += 8) {
        for (int f = tid; f < 8 * 3 * 66; f += 256) {
            int c = f / 198; int rem = f % 198;
            int r = rem / 66; int wi = rem % 66;
            int hh = h + r - 1; int ww = wi - 1;
            float v = 0.f;
            if (hh >= 0 && hh < 64 && ww >= 0 && ww < 64)
                v = xcat[(((size_t)b * 512 + cbase + c0 + c) << 12) + (hh << 6) + ww];
            Xt[c][r][wi] = v;
        }
        for (int f = tid; f < 32 * 72; f += 256) {
            int o = f / 72; int t = f % 72;
            Wt[o][t] = cw[(size_t)(o0 + o) * 2304 + (size_t)c0 * 9 + t];
        }
        __syncthreads();
        #pragma unroll
        for (int c = 0; c < 8; ++c)
            #pragma unroll
            for (int kh = 0; kh < 3; ++kh)
                #pragma unroll
                for (int kw = 0; kw < 3; ++kw) {
                    float xv = Xt[c][kh][w + kw];
                    int wi = c * 9 + kh * 3 + kw;
                    #pragma unroll
                    for (int i = 0; i < 8; ++i)
                        acc[i] += xv * Wt[o4 * 8 + i][wi];
                }
        __syncthreads();
    }

    const float bnsc = 1.0f / sqrtf(1.f + 1e-5f);
    #pragma unroll
    for (int i = 0; i < 8; ++i) {
        int o = o0 + o4 * 8 + i;
        float t = acc[i] + cb[o];
        t = 0.5f * t * (1.f + erff(t * 0.70710678118654752f));
        t = t * (bg[o] * bnsc) + bb[o];
        y1[(((size_t)b * 512 + o) << 12) + (h << 6) + w] = t;
    }
}

// ---------------------------------------------------------------------------
// Horizontal WKV scan (sequence along w). Block = 64 threads = 64 channels at
// one (b,h). k,v tiles staged in LDS; outputs overwrite the k tile for a
// coalesced write-back.
// ---------------------------------------------------------------------------
__global__ __launch_bounds__(64)
void wkv_h_kernel(const float* __restrict__ kin, const float* __restrict__ vin,
                  float* __restrict__ outw,
                  const float* __restrict__ decay, const float* __restrict__ first)
{
    __shared__ float ks[64][65];
    __shared__ float vs[64][65];
    int c0 = blockIdx.x * 64;
    int h  = blockIdx.y;
    int b  = blockIdx.z;
    int tid = threadIdx.x;
    size_t base = (((size_t)b * 256 + c0) * 64 + h) * 64;   // + cc*4096 + w

    for (int f = tid; f < 64 * 64; f += 64) {
        int cc = f >> 6, w = f & 63;
        ks[cc][w] = kin[base + (size_t)cc * 4096 + w];
        vs[cc][w] = vin[base + (size_t)cc * 4096 + w];
    }
    __syncthreads();

    int c = c0 + tid;
    float u  = first[c];
    float wn = -expf(decay[c]);
    float a = 0.f, bb = 0.f, pp = -1e38f;
    for (int t = 0; t < 64; ++t) {
        float kt = ks[tid][t], vt = vs[tid][t];
        float q  = fmaxf(pp, u + kt);
        float e1 = expf(pp - q), e2 = expf(u + kt - q);
        float ov = (e1 * a + e2 * vt) / (e1 * bb + e2);
        ks[tid][t] = ov;
        float q2 = fmaxf(pp + wn, kt);
        float f1 = expf(pp + wn - q2), f2 = expf(kt - q2);
        a = f1 * a + f2 * vt;
        bb = f1 * bb + f2;
        pp = q2;
    }
    __syncthreads();
    for (int f = tid; f < 64 * 64; f += 64) {
        int cc = f >> 6, w = f & 63;
        outw[base + (size_t)cc * 4096 + w] = ks[cc][w];
    }
}

// ---------------------------------------------------------------------------
// Vertical WKV scan (sequence along h), thread per (b,c,w) -> coalesced.
// Combines: outw = 0.5*(outw + scan_v)
// ---------------------------------------------------------------------------
__global__ __launch_bounds__(256)
void wkv_v_kernel(const float* __restrict__ kin, const float* __restrict__ vin,
                  float* __restrict__ outw,
                  const float* __restrict__ decay, const float* __restrict__ first)
{
    int g = blockIdx.x * 256 + threadIdx.x;   // B_*C_*W_ total
    int w = g & 63;
    int c = (g >> 6) & 255;
    int b = g >> 14;
    size_t base = (size_t)(b * 256 + c) * 4096 + w;
    float u  = first[c];
    float wn = -expf(decay[c]);
    float a = 0.f, bb = 0.f, pp = -1e38f;
    for (int h = 0; h < 64; ++h) {
        size_t idx = base + h * 64;
        float kt = kin[idx], vt = vin[idx];
        float q  = fmaxf(pp, u + kt);
        float e1 = expf(pp - q), e2 = expf(u + kt - q);
        float ov = (e1 * a + e2 * vt) / (e1 * bb + e2);
        outw[idx] = 0.5f * (outw[idx] + ov);
        float q2 = fmaxf(pp + wn, kt);
        float f1 = expf(pp + wn - q2), f2 = expf(kt - q2);
        a = f1 * a + f2 * vt;
        bb = f1 * bb + f2;
        pp = q2;
    }
}

// ---------------------------------------------------------------------------
extern "C" void kernel_launch(void* const* d_in, const int* in_sizes, int n_in,
                              void* d_out, int out_size, void* d_ws, size_t ws_size,
                              hipStream_t stream)
{
    const float* x      = (const float*)d_in[0];
    const float* skip   = (const float*)d_in[1];
    const float* mask   = (const float*)d_in[2];
    const float* ln1_w  = (const float*)d_in[3];
    const float* ln1_b  = (const float*)d_in[4];
    const float* ln2_w  = (const float*)d_in[5];
    const float* ln2_b  = (const float*)d_in[6];
    const float* mix_k  = (const float*)d_in[7];
    const float* mix_v  = (const float*)d_in[8];
    const float* mix_r  = (const float*)d_in[9];
    const float* Wk     = (const float*)d_in[10];
    const float* Wv     = (const float*)d_in[11];
    const float* Wr     = (const float*)d_in[12];
    const float* Wo     = (const float*)d_in[13];
    const float* decay  = (const float*)d_in[14];
    const float* first  = (const float*)d_in[15];
    const float* kn_w   = (const float*)d_in[16];
    const float* kn_b   = (const float*)d_in[17];
    const float* sp_w   = (const float*)d_in[18];
    const float* sp_b   = (const float*)d_in[19];
    const float* c1_w   = (const float*)d_in[20];
    const float* c1_b   = (const float*)d_in[21];
    const float* bn1_g  = (const float*)d_in[22];
    const float* bn1_b  = (const float*)d_in[23];
    const float* c2_w   = (const float*)d_in[24];
    const float* c2_b   = (const float*)d_in[25];
    const float* bn2_g  = (const float*)d_in[26];
    const float* bn2_b  = (const float*)d_in[27];
    const float* c3_w   = (const float*)d_in[28];
    const float* c3_b   = (const float*)d_in[29];
    const float* bn3_g  = (const float*)d_in[30];
    const float* bn3_b  = (const float*)d_in[31];
    const float* up_w   = (const float*)d_in[32];
    const float* up_b   = (const float*)d_in[33];
    float* out = (float*)d_out;

    float* ws = (float*)d_ws;
    const size_t S32 = (size_t)B_ * C_ * P_;    // 8,388,608 floats = 32 MB
    // Arena with lifetime-based aliasing; peak = 6*S32 = 192 MB
    float* xn   = ws;            // [0,1)  S32 units
    float* xsh  = ws + S32;      // [1,2)
    float* kbuf = ws + 2 * S32;  // [2,3)
    float* vbuf = ws + 3 * S32;  // [3,4)
    float* wkv  = ws + 4 * S32;  // [4,5)
    float* rbuf = ws + 5 * S32;  // [5,6)
    float* xcat = ws + S32;      // [1,3)  reuses xsh+kbuf (dead)
    float* y1   = ws + 4 * S32;  // [4,6)  reuses wkv+rbuf (dead)
    float* y2   = ws;            // [0,4)  reuses xn,xcat,vbuf (dead)
    float* y3   = ws + 4 * S32;  // [4,5)  reuses y1 (dead)

    dim3 blk(256);

    // 1) LN1
    ln_ch_kernel<<<dim3(B_ * P_ / 256), blk, 0, stream>>>(x, xn, ln1_w, ln1_b, 256);
    // 2) q_shift + saliency blend
    qshift_kernel<<<dim3(B_ * C_ * P_ / 256), blk, 0, stream>>>(xn, mask, xsh);
    // 3) k, v, sr (token-mix fused into GEMM staging)
    gemm1x1_kernel<IN_MIX, EP_NONE><<<dim3(64, 4, 8), blk, 0, stream>>>(
        Wk, xn, xsh, mix_k, nullptr, nullptr, nullptr, nullptr, kbuf, 256, 256, 256, 0);
    gemm1x1_kernel<IN_MIX, EP_NONE><<<dim3(64, 4, 8), blk, 0, stream>>>(
        Wv, xn, xsh, mix_v, nullptr, nullptr, nullptr, nullptr, vbuf, 256, 256, 256, 0);
    gemm1x1_kernel<IN_MIX, EP_SIGMOID><<<dim3(64, 4, 8), blk, 0, stream>>>(
        Wr, xn, xsh, mix_r, nullptr, nullptr, nullptr, nullptr, rbuf, 256, 256, 256, 0);
    // 4) WKV scans: horizontal writes wkv, vertical merges 0.5*(h+v)
    wkv_h_kernel<<<dim3(4, 64, 8), dim3(64), 0, stream>>>(kbuf, vbuf, wkv, decay, first);
    wkv_v_kernel<<<dim3(B_ * C_ * W_ / 256), blk, 0, stream>>>(kbuf, vbuf, wkv, decay, first);
    // 5) key-norm LN (in place)
    ln_ch_kernel<<<dim3(B_ * P_ / 256), blk, 0, stream>>>(wkv, wkv, kn_w, kn_b, 256);
    // 6) x_sg = xn + Wo . (sr * wkv)   -> xcat[:, 0:256]
    gemm1x1_kernel<IN_MUL, EP_RES><<<dim3(64, 4, 8), blk, 0, stream>>>(
        Wo, rbuf, wkv, nullptr, nullptr, nullptr, nullptr, xn, xcat, 256, 256, 512, 0);
    // 7) skip_feat = sp_w . skip + sp_b -> xcat[:, 256:512]
    gemm1x1_kernel<IN_PLAIN, EP_BIAS><<<dim3(64, 4, 8), blk, 0, stream>>>(
        sp_w, skip, nullptr, nullptr, sp_b, nullptr, nullptr, nullptr, xcat, 256, 512, 512, 256);
    // 8) grouped 3x3 conv + gelu + bn1 -> y1
    conv3x3_kernel<<<dim3(64, 16, 8), blk, 0, stream>>>(xcat, c1_w, c1_b, bn1_g, bn1_b, y1);
    // 9) c2 1x1 + gelu + bn2 -> y2
    gemm1x1_kernel<IN_PLAIN, EP_GELU_BN><<<dim3(64, 16, 8), blk, 0, stream>>>(
        c2_w, y1, nullptr, nullptr, c2_b, bn2_g, bn2_b, nullptr, y2, 1024, 512, 1024, 0);
    // 10) c3 1x1 + gelu + bn3 -> y3
    gemm1x1_kernel<IN_PLAIN, EP_GELU_BN><<<dim3(64, 4, 8), blk, 0, stream>>>(
        c3_w, y2, nullptr, nullptr, c3_b, bn3_g, bn3_b, nullptr, y3, 256, 1024, 256, 0);
    // 11) LN2 (in place)
    ln_ch_kernel<<<dim3(B_ * P_ / 256), blk, 0, stream>>>(y3, y3, ln2_w, ln2_b, 256);
    // 12) up-projection + pixel shuffle -> d_out
    gemm1x1_kernel<IN_PLAIN, EP_SHUFFLE><<<dim3(64, 8, 8), blk, 0, stream>>>(
        up_w, y3, nullptr, nullptr, up_b, nullptr, nullptr, nullptr, out, 512, 256, 0, 0);
}

// Round 2
// 1210.891 us; speedup vs baseline: 4.1833x; 4.1833x over previous
//
#include <hip/hip_runtime.h>
#include <hip/hip_bf16.h>
#include <math.h>

#define B_ 8
#define C_ 256
#define H_ 64
#define W_ 64
#define P_ 4096   /* H*W */

typedef __bf16 bf16_t;
typedef __attribute__((ext_vector_type(8))) __bf16 bf16x8;
typedef __attribute__((ext_vector_type(4))) float f32x4;

// ---------------------------------------------------------------------------
// LayerNorm over channel axis
// ---------------------------------------------------------------------------
__global__ __launch_bounds__(256)
void ln_ch_kernel(const float* __restrict__ in, float* __restrict__ out,
                  const float* __restrict__ gw, const float* __restrict__ gb,
                  int C)
{
    int g = blockIdx.x * 256 + threadIdx.x;
    int b = g >> 12;
    int p = g & 4095;
    size_t base = (size_t)b * C * P_ + p;
    float s = 0.f, s2 = 0.f;
    for (int c = 0; c < C; ++c) {
        float x = in[base + (size_t)c * P_];
        s += x; s2 += x * x;
    }
    float mu  = s / C;
    float var = s2 / C - mu * mu;
    float inv = 1.0f / sqrtf(var + 1e-5f);
    for (int c = 0; c < C; ++c) {
        float x = in[base + (size_t)c * P_];
        out[base + (size_t)c * P_] = (x - mu) * inv * gw[c] + gb[c];
    }
}

// ---------------------------------------------------------------------------
// q_shift + saliency blend
// ---------------------------------------------------------------------------
__global__ __launch_bounds__(256)
void qshift_kernel(const float* __restrict__ xn, const float* __restrict__ mask,
                   float* __restrict__ xsh)
{
    int g = blockIdx.x * 256 + threadIdx.x;
    int p = g & 4095;
    int c = (g >> 12) & 255;
    int b = g >> 20;
    int h = p >> 6, w = p & 63;
    float xs = 0.f;
    int quad = c >> 6;
    if (quad == 0)      { if (w > 0)  xs = xn[g - 1];  }
    else if (quad == 1) { if (w < 63) xs = xn[g + 1];  }
    else if (quad == 2) { if (h > 0)  xs = xn[g - 64]; }
    else                { if (h < 63) xs = xn[g + 64]; }
    float m = mask[(b << 12) + p];
    xsh[g] = m * xs + (1.f - m) * xn[g];
}

// ---------------------------------------------------------------------------
// fp32 1x1 GEMM (kept for the small/odd-shaped ops this round)
// ---------------------------------------------------------------------------
#define IN_PLAIN 0
#define IN_MIX   1
#define IN_MUL   2
#define EP_NONE    0
#define EP_SIGMOID 1
#define EP_BIAS    2
#define EP_RES     3
#define EP_SHUFFLE 5

template<int INM, int EPI, int OUTBF>
__global__ __launch_bounds__(256)
void gemm1x1_kernel(const float* __restrict__ Wm,
                    const float* __restrict__ X,
                    const float* __restrict__ X2,
                    const float* __restrict__ mixv,
                    const float* __restrict__ bias,
                    const float* __restrict__ res,
                    void* __restrict__ OutV,
                    int O, int K, int obs, int ocoff)
{
    __shared__ float Ws[16][68];
    __shared__ float Xs[16][64];
    int tid = threadIdx.x;
    int p0 = blockIdx.x * 64;
    int o0 = blockIdx.y * 64;
    int b  = blockIdx.z;
    const float* Xb  = X + (size_t)b * K * P_;
    const float* X2b = (INM != IN_PLAIN) ? (X2 + (size_t)b * K * P_) : nullptr;

    int tx = tid & 15, ty = tid >> 4;
    int wo  = tid >> 2;
    int wc4 = (tid & 3) * 4;
    int xp  = tid & 63;
    int xc  = tid >> 6;

    float acc[4][4] = {};

    for (int k0 = 0; k0 < K; k0 += 16) {
        float4 wv = *reinterpret_cast<const float4*>(&Wm[(size_t)(o0 + wo) * K + k0 + wc4]);
        Ws[wc4 + 0][wo] = wv.x; Ws[wc4 + 1][wo] = wv.y;
        Ws[wc4 + 2][wo] = wv.z; Ws[wc4 + 3][wo] = wv.w;
        #pragma unroll
        for (int j = 0; j < 4; ++j) {
            int c = xc + j * 4;
            size_t idx = (size_t)(k0 + c) * P_ + p0 + xp;
            float v;
            if (INM == IN_PLAIN)      v = Xb[idx];
            else if (INM == IN_MIX) { float m = mixv[k0 + c]; v = m * Xb[idx] + (1.f - m) * X2b[idx]; }
            else                      v = Xb[idx] * X2b[idx];
            Xs[c][xp] = v;
        }
        __syncthreads();
        #pragma unroll
        for (int kk = 0; kk < 16; ++kk) {
            float4 av = *reinterpret_cast<const float4*>(&Ws[kk][ty * 4]);
            float4 xv = *reinterpret_cast<const float4*>(&Xs[kk][tx * 4]);
            float aa[4] = {av.x, av.y, av.z, av.w};
            float xx[4] = {xv.x, xv.y, xv.z, xv.w};
            #pragma unroll
            for (int i = 0; i < 4; ++i)
                #pragma unroll
                for (int j = 0; j < 4; ++j)
                    acc[i][j] += aa[i] * xx[j];
        }
        __syncthreads();
    }

    #pragma unroll
    for (int i = 0; i < 4; ++i) {
        int o = o0 + ty * 4 + i;
        float bi = 0.f;
        if (EPI == EP_BIAS || EPI == EP_SHUFFLE) bi = bias[o];
        #pragma unroll
        for (int j = 0; j < 4; ++j) {
            int p = p0 + tx * 4 + j;
            float t = acc[i][j];
            if (EPI == EP_SIGMOID) t = 1.f / (1.f + expf(-t));
            if (EPI == EP_BIAS)    t += bi;
            if (EPI == EP_RES)     t += res[((size_t)b * 256 + o) * P_ + p];
            if (EPI == EP_SHUFFLE) {
                t += bi;
                int co = o >> 2, s1 = (o >> 1) & 1, s2 = o & 1;
                int h = p >> 6, w = p & 63;
                ((float*)OutV)[(((size_t)b * 128 + co) * 128 + h * 2 + s1) * 128 + w * 2 + s2] = t;
            } else {
                size_t oidx = ((size_t)b * obs + ocoff + o) * P_ + p;
                if (OUTBF) ((bf16_t*)OutV)[oidx] = (bf16_t)t;
                else       ((float*)OutV)[oidx] = t;
            }
        }
    }
}

// ---------------------------------------------------------------------------
// bf16 MFMA implicit-GEMM: CONV=1 -> grouped 3x3 conv (groups=2) over packed
// weights [9][O][256]; CONV=0 -> plain 1x1 over weights [O][K].
// Epilogue: bias + exact GELU + BN-eval; OUTBF selects bf16/fp32 output.
// Tile: 128 out-ch x 64 positions (one h-row), 256 threads = 4 waves (2x2).
// ---------------------------------------------------------------------------
template<int CONV, int OUTBF>
__global__ __launch_bounds__(256)
void mfma_gemm(const bf16_t* __restrict__ Wp, const bf16_t* __restrict__ Xin,
               const float* __restrict__ bias, const float* __restrict__ bng,
               const float* __restrict__ bnb, void* __restrict__ OutV,
               int O, int K, int Cstride)
{
    constexpr int NB = CONV ? 3 : 1;
    __shared__ bf16_t Alds[NB * 128 * 40];   // [tap][o 128][k 32 pad->40]
    __shared__ bf16_t Blds[66 * 40];         // [w+1 (halo)][c 32 pad->40]
    int tid = threadIdx.x;
    int bx = blockIdx.x;
    int o0 = blockIdx.y * 128;
    int b  = blockIdx.z;
    int p0 = bx << 6;
    int cbase = CONV ? ((o0 >> 8) << 8) : 0;
    const bf16_t* Xb = Xin + (size_t)b * Cstride * 4096;

    int lane = tid & 63, wid = tid >> 6;
    int l15 = lane & 15;
    int lk8 = (lane >> 4) << 3;
    int mbase = (wid >> 1) << 6;   // 0 / 64
    int nbase = (wid & 1) << 5;    // 0 / 32

    int tc  = tid >> 3, tw8 = tid & 7;  // B staging: 32c x 8 w-groups
    int ao  = tid >> 1, aq  = tid & 1;  // A staging: 128 rows x 2 quarters

    f32x4 acc[4][2] = {};

    if (tid < 40) { Blds[tid] = (bf16_t)0.f; Blds[65 * 40 + tid] = (bf16_t)0.f; }

    for (int kh = (CONV ? 0 : 1); kh < (CONV ? 3 : 2); ++kh) {
        bool rowok = true;
        int srcp = p0;
        if (CONV) {
            int hh = bx + kh - 1;
            rowok = (hh >= 0) && (hh < 64);
            srcp = hh << 6;
        }
        for (int c0 = 0; c0 < K; c0 += 32) {
            __syncthreads();
            // ---- stage B (once per (kh, c-step)) ----
            bf16x8 bv;
            #pragma unroll
            for (int i = 0; i < 8; ++i) bv[i] = (bf16_t)0.f;
            if (rowok)
                bv = *reinterpret_cast<const bf16x8*>(
                        Xb + (size_t)(cbase + c0 + tc) * 4096 + srcp + tw8 * 8);
            #pragma unroll
            for (int i = 0; i < 8; ++i) Blds[(tw8 * 8 + i + 1) * 40 + tc] = bv[i];
            // ---- stage A (per tap) ----
            #pragma unroll
            for (int t = 0; t < NB; ++t) {
                const bf16_t* wsrc = CONV
                    ? Wp + ((size_t)(kh * 3 + t) * O * 256 + (size_t)(o0 + ao) * 256 + c0)
                    : Wp + ((size_t)(o0 + ao) * K + c0);
                bf16x8 w0 = *reinterpret_cast<const bf16x8*>(wsrc + aq * 8);
                bf16x8 w1 = *reinterpret_cast<const bf16x8*>(wsrc + (aq + 2) * 8);
                *reinterpret_cast<bf16x8*>(&Alds[t * 5120 + ao * 40 + aq * 8]) = w0;
                *reinterpret_cast<bf16x8*>(&Alds[t * 5120 + ao * 40 + (aq + 2) * 8]) = w1;
            }
            __syncthreads();
            // ---- MFMA ----
            #pragma unroll
            for (int t = 0; t < NB; ++t) {
                int kws = CONV ? t : 1;
                bf16x8 af[4], bfv[2];
                #pragma unroll
                for (int i = 0; i < 4; ++i)
                    af[i] = *reinterpret_cast<const bf16x8*>(
                              &Alds[t * 5120 + (mbase + i * 16 + l15) * 40 + lk8]);
                #pragma unroll
                for (int j = 0; j < 2; ++j)
                    bfv[j] = *reinterpret_cast<const bf16x8*>(
                              &Blds[(nbase + j * 16 + l15 + kws) * 40 + lk8]);
                #pragma unroll
                for (int i = 0; i < 4; ++i)
                    #pragma unroll
                    for (int j = 0; j < 2; ++j)
                        acc[i][j] = __builtin_amdgcn_mfma_f32_16x16x32_bf16(
                                        af[i], bfv[j], acc[i][j], 0, 0, 0);
            }
        }
    }

    const float bnsc = 1.0f / sqrtf(1.f + 1e-5f);
    #pragma unroll
    for (int i = 0; i < 4; ++i) {
        #pragma unroll
        for (int r = 0; r < 4; ++r) {
            int o = o0 + mbase + i * 16 + ((lane >> 4) << 2) + r;
            float bi = bias[o];
            float sc = bng[o] * bnsc, sh = bnb[o];
            #pragma unroll
            for (int j = 0; j < 2; ++j) {
                int pp = p0 + nbase + j * 16 + l15;
                float t = acc[i][j][r] + bi;
                t = 0.5f * t * (1.f + erff(t * 0.70710678118654752f));
                t = t * sc + sh;
                size_t oidx = ((size_t)b * O + o) * 4096 + pp;
                if (OUTBF) ((bf16_t*)OutV)[oidx] = (bf16_t)t;
                else       ((float*)OutV)[oidx] = t;
            }
        }
    }
}

// ---------------------------------------------------------------------------
// Weight conversion / repack
// ---------------------------------------------------------------------------
__global__ __launch_bounds__(256)
void repack_conv_w(const float* __restrict__ w, bf16_t* __restrict__ out)
{
    int g = blockIdx.x * 256 + threadIdx.x;   // 9*512*256
    int c = g & 255;
    int o = (g >> 8) & 511;
    int tap = g >> 17;
    out[g] = (bf16_t)w[(size_t)o * 2304 + c * 9 + tap];
}

__global__ __launch_bounds__(256)
void f2bf_kernel(const float* __restrict__ in, bf16_t* __restrict__ out, int n)
{
    int g = blockIdx.x * 256 + threadIdx.x;
    if (g < n) out[g] = (bf16_t)in[g];
}

// ---------------------------------------------------------------------------
// WKV scans
// ---------------------------------------------------------------------------
__global__ __launch_bounds__(64)
void wkv_h_kernel(const float* __restrict__ kin, const float* __restrict__ vin,
                  float* __restrict__ outw,
                  const float* __restrict__ decay, const float* __restrict__ first)
{
    __shared__ float ks[64][65];
    __shared__ float vs[64][65];
    int c0 = blockIdx.x * 64;
    int h  = blockIdx.y;
    int b  = blockIdx.z;
    int tid = threadIdx.x;
    size_t base = (((size_t)b * 256 + c0) * 64 + h) * 64;

    for (int f = tid; f < 64 * 64; f += 64) {
        int cc = f >> 6, w = f & 63;
        ks[cc][w] = kin[base + (size_t)cc * 4096 + w];
        vs[cc][w] = vin[base + (size_t)cc * 4096 + w];
    }
    __syncthreads();

    int c = c0 + tid;
    float u  = first[c];
    float wn = -expf(decay[c]);
    float a = 0.f, bb = 0.f, pp = -1e38f;
    for (int t = 0; t < 64; ++t) {
        float kt = ks[tid][t], vt = vs[tid][t];
        float q  = fmaxf(pp, u + kt);
        float e1 = expf(pp - q), e2 = expf(u + kt - q);
        float ov = (e1 * a + e2 * vt) / (e1 * bb + e2);
        ks[tid][t] = ov;
        float q2 = fmaxf(pp + wn, kt);
        float f1 = expf(pp + wn - q2), f2 = expf(kt - q2);
        a = f1 * a + f2 * vt;
        bb = f1 * bb + f2;
        pp = q2;
    }
    __syncthreads();
    for (int f = tid; f < 64 * 64; f += 64) {
        int cc = f >> 6, w = f & 63;
        outw[base + (size_t)cc * 4096 + w] = ks[cc][w];
    }
}

__global__ __launch_bounds__(256)
void wkv_v_kernel(const float* __restrict__ kin, const float* __restrict__ vin,
                  float* __restrict__ outw,
                  const float* __restrict__ decay, const float* __restrict__ first)
{
    int g = blockIdx.x * 256 + threadIdx.x;
    int w = g & 63;
    int c = (g >> 6) & 255;
    int b = g >> 14;
    size_t base = (size_t)(b * 256 + c) * 4096 + w;
    float u  = first[c];
    float wn = -expf(decay[c]);
    float a = 0.f, bb = 0.f, pp = -1e38f;
    for (int h = 0; h < 64; ++h) {
        size_t idx = base + h * 64;
        float kt = kin[idx], vt = vin[idx];
        float q  = fmaxf(pp, u + kt);
        float e1 = expf(pp - q), e2 = expf(u + kt - q);
        float ov = (e1 * a + e2 * vt) / (e1 * bb + e2);
        outw[idx] = 0.5f * (outw[idx] + ov);
        float q2 = fmaxf(pp + wn, kt);
        float f1 = expf(pp + wn - q2), f2 = expf(kt - q2);
        a = f1 * a + f2 * vt;
        bb = f1 * bb + f2;
        pp = q2;
    }
}

// ---------------------------------------------------------------------------
extern "C" void kernel_launch(void* const* d_in, const int* in_sizes, int n_in,
                              void* d_out, int out_size, void* d_ws, size_t ws_size,
                              hipStream_t stream)
{
    const float* x      = (const float*)d_in[0];
    const float* skip   = (const float*)d_in[1];
    const float* mask   = (const float*)d_in[2];
    const float* ln1_w  = (const float*)d_in[3];
    const float* ln1_b  = (const float*)d_in[4];
    const float* ln2_w  = (const float*)d_in[5];
    const float* ln2_b  = (const float*)d_in[6];
    const float* mix_k  = (const float*)d_in[7];
    const float* mix_v  = (const float*)d_in[8];
    const float* mix_r  = (const float*)d_in[9];
    const float* Wk     = (const float*)d_in[10];
    const float* Wv     = (const float*)d_in[11];
    const float* Wr     = (const float*)d_in[12];
    const float* Wo     = (const float*)d_in[13];
    const float* decay  = (const float*)d_in[14];
    const float* first  = (const float*)d_in[15];
    const float* kn_w   = (const float*)d_in[16];
    const float* kn_b   = (const float*)d_in[17];
    const float* sp_w   = (const float*)d_in[18];
    const float* sp_b   = (const float*)d_in[19];
    const float* c1_w   = (const float*)d_in[20];
    const float* c1_b   = (const float*)d_in[21];
    const float* bn1_g  = (const float*)d_in[22];
    const float* bn1_b  = (const float*)d_in[23];
    const float* c2_w   = (const float*)d_in[24];
    const float* c2_b   = (const float*)d_in[25];
    const float* bn2_g  = (const float*)d_in[26];
    const float* bn2_b  = (const float*)d_in[27];
    const float* c3_w   = (const float*)d_in[28];
    const float* c3_b   = (const float*)d_in[29];
    const float* bn3_g  = (const float*)d_in[30];
    const float* bn3_b  = (const float*)d_in[31];
    const float* up_w   = (const float*)d_in[32];
    const float* up_b   = (const float*)d_in[33];
    float* out = (float*)d_out;

    float* ws = (float*)d_ws;
    const size_t S32 = 8388608;   // 32 MiB of floats
    // Arena (peak 164 MiB):
    float*  xn      = ws;                    // [0,1) S32
    float*  xsh     = ws + S32;              // [1,2) -> later wkv
    float*  wkv     = xsh;
    float*  kbuf    = ws + 2 * S32;          // [2,3)
    float*  vbuf    = ws + 3 * S32;          // [3,4)
    float*  rbuf    = ws + 4 * S32;          // [4,5)
    bf16_t* xcat_bf = (bf16_t*)(ws + 2 * S32);   // [2,3) reuses kbuf (dead)
    bf16_t* y1_bf   = (bf16_t*)(ws + 3 * S32);   // [3,4) reuses vbuf (dead)
    bf16_t* y2_bf   = (bf16_t*)ws;               // [0,2) reuses xn,wkv (dead)
    float*  y3      = ws + 4 * S32;              // [4,5) reuses rbuf (dead)
    bf16_t* wpack9  = (bf16_t*)(ws + 5 * S32);   // 9*512*256 bf16
    bf16_t* c2wb    = wpack9 + 9 * 512 * 256;    // 1024*512
    bf16_t* c3wb    = c2wb + 1024 * 512;         // 256*1024

    dim3 blk(256);

    // 0) weight conversion (deterministic, every call)
    repack_conv_w<<<dim3(9 * 512 * 256 / 256), blk, 0, stream>>>(c1_w, wpack9);
    f2bf_kernel<<<dim3(1024 * 512 / 256), blk, 0, stream>>>(c2_w, c2wb, 1024 * 512);
    f2bf_kernel<<<dim3(256 * 1024 / 256), blk, 0, stream>>>(c3_w, c3wb, 256 * 1024);

    // 1) LN1
    ln_ch_kernel<<<dim3(B_ * P_ / 256), blk, 0, stream>>>(x, xn, ln1_w, ln1_b, 256);
    // 2) q_shift + saliency blend
    qshift_kernel<<<dim3(B_ * C_ * P_ / 256), blk, 0, stream>>>(xn, mask, xsh);
    // 3) k, v, sr
    gemm1x1_kernel<IN_MIX, EP_NONE, 0><<<dim3(64, 4, 8), blk, 0, stream>>>(
        Wk, xn, xsh, mix_k, nullptr, nullptr, kbuf, 256, 256, 256, 0);
    gemm1x1_kernel<IN_MIX, EP_NONE, 0><<<dim3(64, 4, 8), blk, 0, stream>>>(
        Wv, xn, xsh, mix_v, nullptr, nullptr, vbuf, 256, 256, 256, 0);
    gemm1x1_kernel<IN_MIX, EP_SIGMOID, 0><<<dim3(64, 4, 8), blk, 0, stream>>>(
        Wr, xn, xsh, mix_r, nullptr, nullptr, rbuf, 256, 256, 256, 0);
    // 4) WKV scans
    wkv_h_kernel<<<dim3(4, 64, 8), dim3(64), 0, stream>>>(kbuf, vbuf, wkv, decay, first);
    wkv_v_kernel<<<dim3(B_ * C_ * W_ / 256), blk, 0, stream>>>(kbuf, vbuf, wkv, decay, first);
    // 5) key-norm LN (in place)
    ln_ch_kernel<<<dim3(B_ * P_ / 256), blk, 0, stream>>>(wkv, wkv, kn_w, kn_b, 256);
    // 6) x_sg = xn + Wo.(sr*wkv) -> xcat[:,0:256] (bf16)
    gemm1x1_kernel<IN_MUL, EP_RES, 1><<<dim3(64, 4, 8), blk, 0, stream>>>(
        Wo, rbuf, wkv, nullptr, nullptr, xn, xcat_bf, 256, 256, 512, 0);
    // 7) skip_feat -> xcat[:,256:512] (bf16)
    gemm1x1_kernel<IN_PLAIN, EP_BIAS, 1><<<dim3(64, 4, 8), blk, 0, stream>>>(
        sp_w, skip, nullptr, nullptr, sp_b, nullptr, xcat_bf, 256, 512, 512, 256);
    // 8) grouped 3x3 conv + gelu + bn1 -> y1 (bf16, MFMA)
    mfma_gemm<1, 1><<<dim3(64, 4, 8), blk, 0, stream>>>(
        wpack9, xcat_bf, c1_b, bn1_g, bn1_b, y1_bf, 512, 256, 512);
    // 9) c2 + gelu + bn2 -> y2 (bf16, MFMA)
    mfma_gemm<0, 1><<<dim3(64, 8, 8), blk, 0, stream>>>(
        c2wb, y1_bf, c2_b, bn2_g, bn2_b, y2_bf, 1024, 512, 512);
    // 10) c3 + gelu + bn3 -> y3 (fp32 out, MFMA)
    mfma_gemm<0, 0><<<dim3(64, 2, 8), blk, 0, stream>>>(
        c3wb, y2_bf, c3_b, bn3_g, bn3_b, y3, 256, 1024, 1024);
    // 11) LN2 (in place)
    ln_ch_kernel<<<dim3(B_ * P_ / 256), blk, 0, stream>>>(y3, y3, ln2_w, ln2_b, 256);
    // 12) up-projection + pixel shuffle -> d_out
    gemm1x1_kernel<IN_PLAIN, EP_SHUFFLE, 0><<<dim3(64, 8, 8), blk, 0, stream>>>(
        up_w, y3, nullptr, nullptr, up_b, nullptr, out, 512, 256, 0, 0);
}

// Round 3
// 795.983 us; speedup vs baseline: 6.3639x; 1.5213x over previous
//
#include <hip/hip_runtime.h>
#include <hip/hip_bf16.h>
#include <math.h>

#define B_ 8
#define C_ 256
#define P_ 4096

typedef __bf16 bf16_t;
typedef __attribute__((ext_vector_type(8))) __bf16 bf16x8;
typedef __attribute__((ext_vector_type(4))) float f32x4;

// ---------------------------------------------------------------------------
// LayerNorm over channel axis (per (b,p) column, stride P_). In-place safe.
// ---------------------------------------------------------------------------
__global__ __launch_bounds__(256)
void ln_ch_kernel(const float* __restrict__ in, float* __restrict__ out,
                  const float* __restrict__ gw, const float* __restrict__ gb,
                  int C)
{
    int g = blockIdx.x * 256 + threadIdx.x;
    int b = g >> 12;
    int p = g & 4095;
    size_t base = (size_t)b * C * P_ + p;
    float s = 0.f, s2 = 0.f;
    for (int c = 0; c < C; ++c) {
        float x = in[base + (size_t)c * P_];
        s += x; s2 += x * x;
    }
    float mu  = s / C;
    float var = s2 / C - mu * mu;
    float inv = 1.0f / sqrtf(var + 1e-5f);
    for (int c = 0; c < C; ++c) {
        float x = in[base + (size_t)c * P_];
        out[base + (size_t)c * P_] = (x - mu) * inv * gw[c] + gb[c];
    }
}

// ---------------------------------------------------------------------------
// q_shift + saliency blend + 3-way token-mix, emitting bf16 xk/xv/xr directly.
// ---------------------------------------------------------------------------
__global__ __launch_bounds__(256)
void qshift_mix_kernel(const float* __restrict__ xn, const float* __restrict__ mask,
                       const float* __restrict__ mk_, const float* __restrict__ mv_,
                       const float* __restrict__ mr_,
                       bf16_t* __restrict__ xk, bf16_t* __restrict__ xv,
                       bf16_t* __restrict__ xr)
{
    int g = blockIdx.x * 256 + threadIdx.x;
    int p = g & 4095;
    int c = (g >> 12) & 255;
    int b = g >> 20;
    int h = p >> 6, w = p & 63;
    float xs = 0.f;
    int quad = c >> 6;
    if (quad == 0)      { if (w > 0)  xs = xn[g - 1];  }
    else if (quad == 1) { if (w < 63) xs = xn[g + 1];  }
    else if (quad == 2) { if (h > 0)  xs = xn[g - 64]; }
    else                { if (h < 63) xs = xn[g + 64]; }
    float m = mask[(b << 12) + p];
    float xc = xn[g];
    float xsh = m * xs + (1.f - m) * xc;
    float a;
    a = mk_[c]; xk[g] = (bf16_t)(a * xc + (1.f - a) * xsh);
    a = mv_[c]; xv[g] = (bf16_t)(a * xc + (1.f - a) * xsh);
    a = mr_[c]; xr[g] = (bf16_t)(a * xc + (1.f - a) * xsh);
}

// ---------------------------------------------------------------------------
// Unified bf16 MFMA implicit GEMM.
//   NB:    3 = grouped 3x3 conv (packed W [9][O][256]); 1 = 1x1 (W [O][K])
//   BMODE: 0 = bf16 input; 1 = fp32 input (convert); 2 = fp32 a*b (convert)
//   EPI:   epilogues below; OUTBF: bf16/fp32 output
// Tile: 128 o x 64 p (one h row), 256 threads = 4 waves (2x2 of 64x32).
// B staged via 8 coalesced scalar global loads per thread -> one ds_write_b128
// (conflict-free); A staged as b128 rows.
// ---------------------------------------------------------------------------
#define EP_NONE    0
#define EP_SIGMOID 1
#define EP_BIAS    2
#define EP_RES     3
#define EP_GELU_BN 4
#define EP_SHUFFLE 5

template<int NB, int BMODE, int EPI, int OUTBF>
__global__ __launch_bounds__(256)
void mfma_gemm(const bf16_t* __restrict__ Wp, const void* __restrict__ Xin,
               const float* __restrict__ X2, const float* __restrict__ bias,
               const float* __restrict__ bng, const float* __restrict__ bnb,
               const float* __restrict__ res, void* __restrict__ OutV,
               int O, int K, int Cstride, int obs, int ocoff)
{
    __shared__ bf16_t Alds[NB * 128 * 40];   // [tap][o 128][k 32 pad 40]
    __shared__ bf16_t Blds[66 * 40];         // [w halo 66][c 32 pad 40]
    int tid = threadIdx.x;
    int bx = blockIdx.x;
    int o0 = blockIdx.y * 128;
    int b  = blockIdx.z;
    int p0 = bx << 6;
    int cbase = (NB == 3) ? ((o0 >> 8) << 8) : 0;

    int lane = tid & 63, wid = tid >> 6;
    int l15 = lane & 15;
    int lk8 = (lane >> 4) << 3;
    int mbase = (wid >> 1) << 6;   // 0 / 64
    int nbase = (wid & 1) << 5;    // 0 / 32

    int wl = lane;                 // B stage: w position
    int cg = wid;                  // B stage: c octet
    int ao = tid >> 1, aq = tid & 1;

    const bf16_t* Xb_bf = (const bf16_t*)Xin + (size_t)b * Cstride * 4096;
    const float*  Xb_f  = (const float*)Xin + (size_t)b * Cstride * 4096;
    const float*  X2b   = (BMODE == 2) ? X2 + (size_t)b * Cstride * 4096 : nullptr;

    f32x4 acc[4][2] = {};

    if (tid < 40) { Blds[tid] = (bf16_t)0.f; Blds[65 * 40 + tid] = (bf16_t)0.f; }

    for (int kh = 0; kh < NB; ++kh) {
        bool rowok = true;
        int srcp = p0;
        if (NB == 3) {
            int hh = bx + kh - 1;
            rowok = (hh >= 0) && (hh < 64);
            srcp = hh << 6;
        }
        for (int c0 = 0; c0 < K; c0 += 32) {
            __syncthreads();
            // ---- stage B: 8 channels x 64 w, coalesced loads, b128 write ----
            bf16x8 bv;
            #pragma unroll
            for (int i = 0; i < 8; ++i) bv[i] = (bf16_t)0.f;
            if (rowok) {
                size_t gbase = (size_t)(cbase + c0 + cg * 8) * 4096 + srcp + wl;
                #pragma unroll
                for (int j = 0; j < 8; ++j) {
                    size_t gi = gbase + (size_t)j * 4096;
                    if (BMODE == 0)      bv[j] = Xb_bf[gi];
                    else if (BMODE == 1) bv[j] = (bf16_t)Xb_f[gi];
                    else                 bv[j] = (bf16_t)(Xb_f[gi] * X2b[gi]);
                }
            }
            *reinterpret_cast<bf16x8*>(&Blds[(wl + 1) * 40 + cg * 8]) = bv;
            // ---- stage A ----
            #pragma unroll
            for (int t = 0; t < NB; ++t) {
                const bf16_t* wsrc = (NB == 3)
                    ? Wp + ((size_t)(kh * 3 + t) * O + o0 + ao) * 256 + c0
                    : Wp + (size_t)(o0 + ao) * K + c0;
                bf16x8 w0 = *reinterpret_cast<const bf16x8*>(wsrc + aq * 8);
                bf16x8 w1 = *reinterpret_cast<const bf16x8*>(wsrc + (aq + 2) * 8);
                *reinterpret_cast<bf16x8*>(&Alds[t * 5120 + ao * 40 + aq * 8]) = w0;
                *reinterpret_cast<bf16x8*>(&Alds[t * 5120 + ao * 40 + (aq + 2) * 8]) = w1;
            }
            __syncthreads();
            // ---- MFMA ----
            #pragma unroll
            for (int t = 0; t < NB; ++t) {
                int kws = (NB == 3) ? t : 1;
                bf16x8 af[4], bfv[2];
                #pragma unroll
                for (int i = 0; i < 4; ++i)
                    af[i] = *reinterpret_cast<const bf16x8*>(
                              &Alds[t * 5120 + (mbase + i * 16 + l15) * 40 + lk8]);
                #pragma unroll
                for (int j = 0; j < 2; ++j)
                    bfv[j] = *reinterpret_cast<const bf16x8*>(
                              &Blds[(nbase + j * 16 + l15 + kws) * 40 + lk8]);
                #pragma unroll
                for (int i = 0; i < 4; ++i)
                    #pragma unroll
                    for (int j = 0; j < 2; ++j)
                        acc[i][j] = __builtin_amdgcn_mfma_f32_16x16x32_bf16(
                                        af[i], bfv[j], acc[i][j], 0, 0, 0);
            }
        }
    }

    const float bnsc = 1.0f / sqrtf(1.f + 1e-5f);
    #pragma unroll
    for (int i = 0; i < 4; ++i) {
        #pragma unroll
        for (int r = 0; r < 4; ++r) {
            int o = o0 + mbase + i * 16 + ((lane >> 4) << 2) + r;
            float bi = (EPI == EP_BIAS || EPI == EP_GELU_BN || EPI == EP_SHUFFLE)
                       ? bias[o] : 0.f;
            float sc = 0.f, sh = 0.f;
            if (EPI == EP_GELU_BN) { sc = bng[o] * bnsc; sh = bnb[o]; }
            #pragma unroll
            for (int j = 0; j < 2; ++j) {
                int pp = p0 + nbase + j * 16 + l15;
                float t = acc[i][j][r];
                if (EPI == EP_SIGMOID) t = 1.f / (1.f + expf(-t));
                if (EPI == EP_BIAS || EPI == EP_GELU_BN || EPI == EP_SHUFFLE) t += bi;
                if (EPI == EP_RES) t += res[((size_t)b * 256 + o) * 4096 + pp];
                if (EPI == EP_GELU_BN) {
                    t = 0.5f * t * (1.f + erff(t * 0.70710678118654752f));
                    t = t * sc + sh;
                }
                if (EPI == EP_SHUFFLE) {
                    int co = o >> 2, s1 = (o >> 1) & 1, s2 = o & 1;
                    int hh = pp >> 6, ww = pp & 63;
                    ((float*)OutV)[(((size_t)b * 128 + co) * 128 + hh * 2 + s1) * 128
                                   + ww * 2 + s2] = t;
                } else {
                    size_t oidx = ((size_t)b * obs + ocoff + o) * 4096 + pp;
                    if (OUTBF) ((bf16_t*)OutV)[oidx] = (bf16_t)t;
                    else       ((float*)OutV)[oidx]  = t;
                }
            }
        }
    }
}

// ---------------------------------------------------------------------------
// Weight packing
// ---------------------------------------------------------------------------
__global__ __launch_bounds__(256)
void repack_conv_w(const float* __restrict__ w, bf16_t* __restrict__ out)
{
    int g = blockIdx.x * 256 + threadIdx.x;   // 9*512*256
    int c = g & 255;
    int o = (g >> 8) & 511;
    int tap = g >> 17;
    out[g] = (bf16_t)w[(size_t)o * 2304 + c * 9 + tap];
}

__global__ __launch_bounds__(256)
void pack_weights(const float* __restrict__ wk, const float* __restrict__ wv,
                  const float* __restrict__ wr, const float* __restrict__ wo,
                  const float* __restrict__ sp, const float* __restrict__ c2,
                  const float* __restrict__ c3, const float* __restrict__ up,
                  bf16_t* __restrict__ out)
{
    int g = blockIdx.x * 256 + threadIdx.x;   // 1310720 total
    float v;
    if      (g < 65536)   v = wk[g];
    else if (g < 131072)  v = wv[g - 65536];
    else if (g < 196608)  v = wr[g - 131072];
    else if (g < 262144)  v = wo[g - 196608];
    else if (g < 393216)  v = sp[g - 262144];
    else if (g < 917504)  v = c2[g - 393216];
    else if (g < 1179648) v = c3[g - 917504];
    else                  v = up[g - 1179648];
    out[g] = (bf16_t)v;
}

// ---------------------------------------------------------------------------
// WKV scans
// ---------------------------------------------------------------------------
__global__ __launch_bounds__(64)
void wkv_h_kernel(const float* __restrict__ kin, const float* __restrict__ vin,
                  float* __restrict__ outw,
                  const float* __restrict__ decay, const float* __restrict__ first)
{
    __shared__ float ks[64][65];
    __shared__ float vs[64][65];
    int c0 = blockIdx.x * 64;
    int h  = blockIdx.y;
    int b  = blockIdx.z;
    int tid = threadIdx.x;
    size_t base = (((size_t)b * 256 + c0) * 64 + h) * 64;

    for (int f = tid; f < 64 * 64; f += 64) {
        int cc = f >> 6, w = f & 63;
        ks[cc][w] = kin[base + (size_t)cc * 4096 + w];
        vs[cc][w] = vin[base + (size_t)cc * 4096 + w];
    }
    __syncthreads();

    int c = c0 + tid;
    float u  = first[c];
    float wn = -expf(decay[c]);
    float a = 0.f, bb = 0.f, pp = -1e38f;
    for (int t = 0; t < 64; ++t) {
        float kt = ks[tid][t], vt = vs[tid][t];
        float q  = fmaxf(pp, u + kt);
        float e1 = expf(pp - q), e2 = expf(u + kt - q);
        float ov = (e1 * a + e2 * vt) / (e1 * bb + e2);
        ks[tid][t] = ov;
        float q2 = fmaxf(pp + wn, kt);
        float f1 = expf(pp + wn - q2), f2 = expf(kt - q2);
        a = f1 * a + f2 * vt;
        bb = f1 * bb + f2;
        pp = q2;
    }
    __syncthreads();
    for (int f = tid; f < 64 * 64; f += 64) {
        int cc = f >> 6, w = f & 63;
        outw[base + (size_t)cc * 4096 + w] = ks[cc][w];
    }
}

__global__ __launch_bounds__(256)
void wkv_v_kernel(const float* __restrict__ kin, const float* __restrict__ vin,
                  float* __restrict__ outw,
                  const float* __restrict__ decay, const float* __restrict__ first)
{
    int g = blockIdx.x * 256 + threadIdx.x;
    int w = g & 63;
    int c = (g >> 6) & 255;
    int b = g >> 14;
    size_t base = (size_t)(b * 256 + c) * 4096 + w;
    float u  = first[c];
    float wn = -expf(decay[c]);
    float a = 0.f, bb = 0.f, pp = -1e38f;
    for (int h = 0; h < 64; ++h) {
        size_t idx = base + h * 64;
        float kt = kin[idx], vt = vin[idx];
        float q  = fmaxf(pp, u + kt);
        float e1 = expf(pp - q), e2 = expf(u + kt - q);
        float ov = (e1 * a + e2 * vt) / (e1 * bb + e2);
        outw[idx] = 0.5f * (outw[idx] + ov);
        float q2 = fmaxf(pp + wn, kt);
        float f1 = expf(pp + wn - q2), f2 = expf(kt - q2);
        a = f1 * a + f2 * vt;
        bb = f1 * bb + f2;
        pp = q2;
    }
}

// ---------------------------------------------------------------------------
extern "C" void kernel_launch(void* const* d_in, const int* in_sizes, int n_in,
                              void* d_out, int out_size, void* d_ws, size_t ws_size,
                              hipStream_t stream)
{
    const float* x      = (const float*)d_in[0];
    const float* skip   = (const float*)d_in[1];
    const float* mask   = (const float*)d_in[2];
    const float* ln1_w  = (const float*)d_in[3];
    const float* ln1_b  = (const float*)d_in[4];
    const float* ln2_w  = (const float*)d_in[5];
    const float* ln2_b  = (const float*)d_in[6];
    const float* mix_k  = (const float*)d_in[7];
    const float* mix_v  = (const float*)d_in[8];
    const float* mix_r  = (const float*)d_in[9];
    const float* Wk     = (const float*)d_in[10];
    const float* Wv     = (const float*)d_in[11];
    const float* Wr     = (const float*)d_in[12];
    const float* Wo     = (const float*)d_in[13];
    const float* decay  = (const float*)d_in[14];
    const float* first  = (const float*)d_in[15];
    const float* kn_w   = (const float*)d_in[16];
    const float* kn_b   = (const float*)d_in[17];
    const float* sp_w   = (const float*)d_in[18];
    const float* sp_b   = (const float*)d_in[19];
    const float* c1_w   = (const float*)d_in[20];
    const float* c1_b   = (const float*)d_in[21];
    const float* bn1_g  = (const float*)d_in[22];
    const float* bn1_b  = (const float*)d_in[23];
    const float* c2_w   = (const float*)d_in[24];
    const float* c2_b   = (const float*)d_in[25];
    const float* bn2_g  = (const float*)d_in[26];
    const float* bn2_b  = (const float*)d_in[27];
    const float* c3_w   = (const float*)d_in[28];
    const float* c3_b   = (const float*)d_in[29];
    const float* bn3_g  = (const float*)d_in[30];
    const float* bn3_b  = (const float*)d_in[31];
    const float* up_w   = (const float*)d_in[32];
    const float* up_b   = (const float*)d_in[33];
    float* out = (float*)d_out;

    float* ws = (float*)d_ws;
    const size_t S = 8388608;   // 32 MiB of floats
    // Arena (peak ~181 MiB); lifetimes annotated.
    float*  xn   = ws;                              // [0,1S) live until Wo
    bf16_t* xk   = (bf16_t*)(ws + S);               // [1,1.5S) until k GEMM
    bf16_t* xv   = (bf16_t*)(ws + S + S / 2);       // [1.5,2S) until v GEMM
    bf16_t* xr   = (bf16_t*)(ws + 2 * S);           // [2,2.5S) until r GEMM
    float*  kbuf = ws + 2 * S + S / 2;              // [2.5,3.5S) until scans
    float*  vbuf = ws + 3 * S + S / 2;              // [3.5,4.5S) until scans
    float*  rbuf = ws + 4 * S + S / 2;              // [4.5,5.5S) until Wo
    float*  wkv  = ws + S;                          // [1,2S) reuse xk/xv
    bf16_t* xcat = (bf16_t*)(ws + 2 * S + S / 2);   // [2.5,3.5S) reuse kbuf
    bf16_t* y1   = (bf16_t*)(ws + 3 * S + S / 2);   // [3.5,4.5S) reuse vbuf
    bf16_t* y2   = (bf16_t*)ws;                     // [0,2S) reuse xn+wkv
    float*  y3   = ws + 4 * S + S / 2;              // [4.5,5.5S) reuse rbuf
    bf16_t* w9   = (bf16_t*)(ws + 5 * S + S / 2);   // conv weights 9*512*256
    bf16_t* wfl  = w9 + 9 * 512 * 256;              // packed 1x1 weights
    bf16_t* wkb = wfl;
    bf16_t* wvb = wfl + 65536;
    bf16_t* wrb = wfl + 131072;
    bf16_t* wob = wfl + 196608;
    bf16_t* spb = wfl + 262144;
    bf16_t* c2b = wfl + 393216;
    bf16_t* c3b = wfl + 917504;
    bf16_t* upb = wfl + 1179648;

    dim3 blk(256);

    // 0) weight packing
    pack_weights<<<dim3(5120), blk, 0, stream>>>(Wk, Wv, Wr, Wo, sp_w, c2_w, c3_w, up_w, wfl);
    repack_conv_w<<<dim3(4608), blk, 0, stream>>>(c1_w, w9);

    // 1) LN1
    ln_ch_kernel<<<dim3(128), blk, 0, stream>>>(x, xn, ln1_w, ln1_b, 256);
    // 2) q_shift + blend + mix -> xk/xv/xr (bf16)
    qshift_mix_kernel<<<dim3(32768), blk, 0, stream>>>(xn, mask, mix_k, mix_v, mix_r,
                                                       xk, xv, xr);
    // 3) k, v, sr (MFMA)
    mfma_gemm<1, 0, EP_NONE, 0><<<dim3(64, 2, 8), blk, 0, stream>>>(
        wkb, xk, nullptr, nullptr, nullptr, nullptr, nullptr, kbuf, 256, 256, 256, 256, 0);
    mfma_gemm<1, 0, EP_NONE, 0><<<dim3(64, 2, 8), blk, 0, stream>>>(
        wvb, xv, nullptr, nullptr, nullptr, nullptr, nullptr, vbuf, 256, 256, 256, 256, 0);
    mfma_gemm<1, 0, EP_SIGMOID, 0><<<dim3(64, 2, 8), blk, 0, stream>>>(
        wrb, xr, nullptr, nullptr, nullptr, nullptr, nullptr, rbuf, 256, 256, 256, 256, 0);
    // 4) WKV scans (h writes, v merges 0.5*(h+v))
    wkv_h_kernel<<<dim3(4, 64, 8), dim3(64), 0, stream>>>(kbuf, vbuf, wkv, decay, first);
    wkv_v_kernel<<<dim3(512), blk, 0, stream>>>(kbuf, vbuf, wkv, decay, first);
    // 5) key-norm LN (in place)
    ln_ch_kernel<<<dim3(128), blk, 0, stream>>>(wkv, wkv, kn_w, kn_b, 256);
    // 6) x_sg = xn + Wo.(sr*wkv) -> xcat[:,0:256]
    mfma_gemm<1, 2, EP_RES, 1><<<dim3(64, 2, 8), blk, 0, stream>>>(
        wob, rbuf, wkv, nullptr, nullptr, nullptr, xn, xcat, 256, 256, 256, 512, 0);
    // 7) skip_feat -> xcat[:,256:512]
    mfma_gemm<1, 1, EP_BIAS, 1><<<dim3(64, 2, 8), blk, 0, stream>>>(
        spb, skip, nullptr, sp_b, nullptr, nullptr, nullptr, xcat, 256, 512, 512, 512, 256);
    // 8) grouped 3x3 conv + gelu + bn1 -> y1
    mfma_gemm<3, 0, EP_GELU_BN, 1><<<dim3(64, 4, 8), blk, 0, stream>>>(
        w9, xcat, nullptr, c1_b, bn1_g, bn1_b, nullptr, y1, 512, 256, 512, 512, 0);
    // 9) c2 + gelu + bn2 -> y2
    mfma_gemm<1, 0, EP_GELU_BN, 1><<<dim3(64, 8, 8), blk, 0, stream>>>(
        c2b, y1, nullptr, c2_b, bn2_g, bn2_b, nullptr, y2, 1024, 512, 512, 1024, 0);
    // 10) c3 + gelu + bn3 -> y3 (fp32)
    mfma_gemm<1, 0, EP_GELU_BN, 0><<<dim3(64, 2, 8), blk, 0, stream>>>(
        c3b, y2, nullptr, c3_b, bn3_g, bn3_b, nullptr, y3, 256, 1024, 1024, 256, 0);
    // 11) LN2 (in place)
    ln_ch_kernel<<<dim3(128), blk, 0, stream>>>(y3, y3, ln2_w, ln2_b, 256);
    // 12) up-projection + pixel shuffle -> out
    mfma_gemm<1, 1, EP_SHUFFLE, 0><<<dim3(64, 4, 8), blk, 0, stream>>>(
        upb, y3, nullptr, up_b, nullptr, nullptr, nullptr, out, 512, 256, 256, 0, 0);
}

// Round 4
// 527.815 us; speedup vs baseline: 9.5973x; 1.5081x over previous
//
#include <hip/hip_runtime.h>
#include <hip/hip_bf16.h>
#include <math.h>

#define B_ 8
#define C_ 256
#define P_ 4096

typedef __bf16 bf16_t;
typedef __attribute__((ext_vector_type(8))) __bf16 bf16x8;
typedef __attribute__((ext_vector_type(4))) float f32x4;

// ---------------------------------------------------------------------------
// Channel-LN stats: per (b,p) mean and 1/sqrt(var+eps) over C=256 channels.
// Block = 64 p-positions x 4 c-chunks; grid = B*P/64 = 512.
// ---------------------------------------------------------------------------
__global__ __launch_bounds__(256)
void ln_stats_kernel(const float* __restrict__ in, float2* __restrict__ stats)
{
    __shared__ float sred[4][64];
    __shared__ float s2red[4][64];
    int tid = threadIdx.x;
    int wp = tid & 63, cw = tid >> 6;
    int gp = blockIdx.x * 64 + wp;          // b*4096 + p
    int b  = gp >> 12, p = gp & 4095;
    size_t base = (size_t)b * 256 * 4096 + p;
    float s = 0.f, s2 = 0.f;
    #pragma unroll 8
    for (int cc = 0; cc < 64; ++cc) {
        float v = in[base + (size_t)(cw * 64 + cc) * 4096];
        s += v; s2 += v * v;
    }
    sred[cw][wp] = s; s2red[cw][wp] = s2;
    __syncthreads();
    if (cw == 0) {
        s  = sred[0][wp]  + sred[1][wp]  + sred[2][wp]  + sred[3][wp];
        s2 = s2red[0][wp] + s2red[1][wp] + s2red[2][wp] + s2red[3][wp];
        float mu  = s * (1.f / 256.f);
        float var = s2 * (1.f / 256.f) - mu * mu;
        stats[gp] = make_float2(mu, 1.0f / sqrtf(var + 1e-5f));
    }
}

// ---------------------------------------------------------------------------
// Fused: LN1(on-the-fly) + q_shift + saliency blend + 3-way token-mix -> bf16
// ---------------------------------------------------------------------------
__global__ __launch_bounds__(256)
void qshift_mix_kernel(const float* __restrict__ x, const float2* __restrict__ st1,
                       const float* __restrict__ mask,
                       const float* __restrict__ gw, const float* __restrict__ gb,
                       const float* __restrict__ mk_, const float* __restrict__ mv_,
                       const float* __restrict__ mr_,
                       bf16_t* __restrict__ xk, bf16_t* __restrict__ xv,
                       bf16_t* __restrict__ xr)
{
    int g = blockIdx.x * 256 + threadIdx.x;
    int p = g & 4095;
    int c = (g >> 12) & 255;
    int b = g >> 20;
    int h = p >> 6, w = p & 63;
    float gwc = gw[c], gbc = gb[c];
    float2 stc = st1[(b << 12) + p];
    float xcv = (x[g] - stc.x) * stc.y * gwc + gbc;
    float xs = 0.f;
    int quad = c >> 6;
    int d = 0; bool ok = false;
    if (quad == 0)      { ok = (w > 0);  d = -1;  }
    else if (quad == 1) { ok = (w < 63); d = 1;   }
    else if (quad == 2) { ok = (h > 0);  d = -64; }
    else                { ok = (h < 63); d = 64;  }
    if (ok) {
        float2 st2 = st1[(b << 12) + p + d];
        xs = (x[g + d] - st2.x) * st2.y * gwc + gbc;
    }
    float m = mask[(b << 12) + p];
    float xsh = m * xs + (1.f - m) * xcv;
    float a;
    a = mk_[c]; xk[g] = (bf16_t)(a * xcv + (1.f - a) * xsh);
    a = mv_[c]; xv[g] = (bf16_t)(a * xcv + (1.f - a) * xsh);
    a = mr_[c]; xr[g] = (bf16_t)(a * xcv + (1.f - a) * xsh);
}

// ---------------------------------------------------------------------------
// Unified bf16 MFMA implicit GEMM.
//   NB: 3 = grouped 3x3 conv (W packed [9][O][256]); 1 = 1x1
//   BMODE: 0 bf16 | 1 f32 | 2 f32 LN | 3 X2 * (f32 LN)
//   EPI: 0 none | 1 sigmoid | 2 +bias | 3 +LN(resx) | 4 gelu+bn | 5 shuffle
// ---------------------------------------------------------------------------
#define EP_NONE    0
#define EP_SIGMOID 1
#define EP_BIAS    2
#define EP_RESLN   3
#define EP_GELU_BN 4
#define EP_SHUFFLE 5

template<int NB, int BMODE, int EPI, int OUTBF>
__global__ __launch_bounds__(256)
void mfma_gemm(const bf16_t* __restrict__ Wp, const void* __restrict__ Xin,
               const float* __restrict__ X2,
               const float2* __restrict__ bstats, const float* __restrict__ blnw,
               const float* __restrict__ blnb,
               const float* __restrict__ bias, const float* __restrict__ bng,
               const float* __restrict__ bnb,
               const float* __restrict__ resx, const float2* __restrict__ estats,
               const float* __restrict__ elnw, const float* __restrict__ elnb,
               void* __restrict__ OutV,
               int O, int K, int Cstride, int obs, int ocoff)
{
    __shared__ bf16_t Alds[NB * 128 * 40];
    __shared__ bf16_t Blds[66 * 40];
    int tid = threadIdx.x;
    int bx = blockIdx.x;
    int o0 = blockIdx.y * 128;
    int b  = blockIdx.z;
    int p0 = bx << 6;
    int cbase = (NB == 3) ? ((o0 >> 8) << 8) : 0;

    int lane = tid & 63, wid = tid >> 6;
    int l15 = lane & 15;
    int lk8 = (lane >> 4) << 3;
    int mbase = (wid >> 1) << 6;
    int nbase = (wid & 1) << 5;

    int wl = lane;
    int cg = wid;
    int ao = tid >> 1, aq = tid & 1;

    const bf16_t* Xb_bf = (const bf16_t*)Xin + (size_t)b * Cstride * 4096;
    const float*  Xb_f  = (const float*)Xin + (size_t)b * Cstride * 4096;
    const float*  X2b   = (BMODE == 3) ? X2 + (size_t)b * Cstride * 4096 : nullptr;

    f32x4 acc[4][2] = {};

    if (tid < 40) { Blds[tid] = (bf16_t)0.f; Blds[65 * 40 + tid] = (bf16_t)0.f; }

    for (int kh = 0; kh < NB; ++kh) {
        bool rowok = true;
        int srcp = p0;
        if (NB == 3) {
            int hh = bx + kh - 1;
            rowok = (hh >= 0) && (hh < 64);
            srcp = hh << 6;
        }
        for (int c0 = 0; c0 < K; c0 += 32) {
            __syncthreads();
            // ---- stage B ----
            bf16x8 bv;
            #pragma unroll
            for (int i = 0; i < 8; ++i) bv[i] = (bf16_t)0.f;
            if (rowok) {
                size_t gbase = (size_t)(cbase + c0 + cg * 8) * 4096 + srcp + wl;
                float2 st = make_float2(0.f, 0.f);
                if (BMODE >= 2) st = bstats[(b << 12) + srcp + wl];
                #pragma unroll
                for (int j = 0; j < 8; ++j) {
                    size_t gi = gbase + (size_t)j * 4096;
                    int cc = c0 + cg * 8 + j;
                    if (BMODE == 0)      bv[j] = Xb_bf[gi];
                    else if (BMODE == 1) bv[j] = (bf16_t)Xb_f[gi];
                    else {
                        float v = (Xb_f[gi] - st.x) * st.y * blnw[cc] + blnb[cc];
                        if (BMODE == 3) v *= X2b[gi];
                        bv[j] = (bf16_t)v;
                    }
                }
            }
            *reinterpret_cast<bf16x8*>(&Blds[(wl + 1) * 40 + cg * 8]) = bv;
            // ---- stage A ----
            #pragma unroll
            for (int t = 0; t < NB; ++t) {
                const bf16_t* wsrc = (NB == 3)
                    ? Wp + ((size_t)(kh * 3 + t) * O + o0 + ao) * 256 + c0
                    : Wp + (size_t)(o0 + ao) * K + c0;
                bf16x8 w0 = *reinterpret_cast<const bf16x8*>(wsrc + aq * 8);
                bf16x8 w1 = *reinterpret_cast<const bf16x8*>(wsrc + (aq + 2) * 8);
                *reinterpret_cast<bf16x8*>(&Alds[t * 5120 + ao * 40 + aq * 8]) = w0;
                *reinterpret_cast<bf16x8*>(&Alds[t * 5120 + ao * 40 + (aq + 2) * 8]) = w1;
            }
            __syncthreads();
            // ---- MFMA ----
            #pragma unroll
            for (int t = 0; t < NB; ++t) {
                int kws = (NB == 3) ? t : 1;
                bf16x8 af[4], bfv[2];
                #pragma unroll
                for (int i = 0; i < 4; ++i)
                    af[i] = *reinterpret_cast<const bf16x8*>(
                              &Alds[t * 5120 + (mbase + i * 16 + l15) * 40 + lk8]);
                #pragma unroll
                for (int j = 0; j < 2; ++j)
                    bfv[j] = *reinterpret_cast<const bf16x8*>(
                              &Blds[(nbase + j * 16 + l15 + kws) * 40 + lk8]);
                #pragma unroll
                for (int i = 0; i < 4; ++i)
                    #pragma unroll
                    for (int j = 0; j < 2; ++j)
                        acc[i][j] = __builtin_amdgcn_mfma_f32_16x16x32_bf16(
                                        af[i], bfv[j], acc[i][j], 0, 0, 0);
            }
        }
    }

    const float bnsc = 1.0f / sqrtf(1.f + 1e-5f);
    #pragma unroll
    for (int i = 0; i < 4; ++i) {
        #pragma unroll
        for (int r = 0; r < 4; ++r) {
            int o = o0 + mbase + i * 16 + ((lane >> 4) << 2) + r;
            float bi = (EPI == EP_BIAS || EPI == EP_GELU_BN || EPI == EP_SHUFFLE)
                       ? bias[o] : 0.f;
            float sc = 0.f, sh = 0.f;
            if (EPI == EP_GELU_BN) { sc = bng[o] * bnsc; sh = bnb[o]; }
            float rw = 0.f, rb = 0.f;
            if (EPI == EP_RESLN) { rw = elnw[o]; rb = elnb[o]; }
            #pragma unroll
            for (int j = 0; j < 2; ++j) {
                int pp = p0 + nbase + j * 16 + l15;
                float t = acc[i][j][r];
                if (EPI == EP_SIGMOID) t = 1.f / (1.f + expf(-t));
                if (EPI == EP_BIAS || EPI == EP_GELU_BN || EPI == EP_SHUFFLE) t += bi;
                if (EPI == EP_RESLN) {
                    float2 st = estats[(b << 12) + pp];
                    float rv = resx[((size_t)b * 256 + o) * 4096 + pp];
                    t += (rv - st.x) * st.y * rw + rb;
                }
                if (EPI == EP_GELU_BN) {
                    t = 0.5f * t * (1.f + erff(t * 0.70710678118654752f));
                    t = t * sc + sh;
                }
                if (EPI == EP_SHUFFLE) {
                    int co = o >> 2, s1 = (o >> 1) & 1, s2 = o & 1;
                    int hh = pp >> 6, ww = pp & 63;
                    ((float*)OutV)[(((size_t)b * 128 + co) * 128 + hh * 2 + s1) * 128
                                   + ww * 2 + s2] = t;
                } else {
                    size_t oidx = ((size_t)b * obs + ocoff + o) * 4096 + pp;
                    if (OUTBF) ((bf16_t*)OutV)[oidx] = (bf16_t)t;
                    else       ((float*)OutV)[oidx]  = t;
                }
            }
        }
    }
}

// ---------------------------------------------------------------------------
// Weight packing
// ---------------------------------------------------------------------------
__global__ __launch_bounds__(256)
void repack_conv_w(const float* __restrict__ w, bf16_t* __restrict__ out)
{
    int g = blockIdx.x * 256 + threadIdx.x;
    int c = g & 255;
    int o = (g >> 8) & 511;
    int tap = g >> 17;
    out[g] = (bf16_t)w[(size_t)o * 2304 + c * 9 + tap];
}

__global__ __launch_bounds__(256)
void pack_weights(const float* __restrict__ wk, const float* __restrict__ wv,
                  const float* __restrict__ wr, const float* __restrict__ wo,
                  const float* __restrict__ sp, const float* __restrict__ c2,
                  const float* __restrict__ c3, const float* __restrict__ up,
                  bf16_t* __restrict__ out)
{
    int g = blockIdx.x * 256 + threadIdx.x;
    float v;
    if      (g < 65536)   v = wk[g];
    else if (g < 131072)  v = wv[g - 65536];
    else if (g < 196608)  v = wr[g - 131072];
    else if (g < 262144)  v = wo[g - 196608];
    else if (g < 393216)  v = sp[g - 262144];
    else if (g < 917504)  v = c2[g - 393216];
    else if (g < 1179648) v = c3[g - 917504];
    else                  v = up[g - 1179648];
    out[g] = (bf16_t)v;
}

// ---------------------------------------------------------------------------
// WKV scans
// ---------------------------------------------------------------------------
__global__ __launch_bounds__(64)
void wkv_h_kernel(const float* __restrict__ kin, const float* __restrict__ vin,
                  float* __restrict__ outw,
                  const float* __restrict__ decay, const float* __restrict__ first)
{
    __shared__ float ks[64][65];
    __shared__ float vs[64][65];
    int c0 = blockIdx.x * 64;
    int h  = blockIdx.y;
    int b  = blockIdx.z;
    int tid = threadIdx.x;
    size_t base = (((size_t)b * 256 + c0) * 64 + h) * 64;

    for (int f = tid; f < 64 * 64; f += 64) {
        int cc = f >> 6, w = f & 63;
        ks[cc][w] = kin[base + (size_t)cc * 4096 + w];
        vs[cc][w] = vin[base + (size_t)cc * 4096 + w];
    }
    __syncthreads();

    int c = c0 + tid;
    float u  = first[c];
    float wn = -expf(decay[c]);
    float a = 0.f, bb = 0.f, pp = -1e38f;
    for (int t = 0; t < 64; ++t) {
        float kt = ks[tid][t], vt = vs[tid][t];
        float q  = fmaxf(pp, u + kt);
        float e1 = expf(pp - q), e2 = expf(u + kt - q);
        float ov = (e1 * a + e2 * vt) / (e1 * bb + e2);
        ks[tid][t] = ov;
        float q2 = fmaxf(pp + wn, kt);
        float f1 = expf(pp + wn - q2), f2 = expf(kt - q2);
        a = f1 * a + f2 * vt;
        bb = f1 * bb + f2;
        pp = q2;
    }
    __syncthreads();
    for (int f = tid; f < 64 * 64; f += 64) {
        int cc = f >> 6, w = f & 63;
        outw[base + (size_t)cc * 4096 + w] = ks[cc][w];
    }
}

__global__ __launch_bounds__(256)
void wkv_v_kernel(const float* __restrict__ kin, const float* __restrict__ vin,
                  float* __restrict__ outw,
                  const float* __restrict__ decay, const float* __restrict__ first)
{
    int g = blockIdx.x * 256 + threadIdx.x;
    int w = g & 63;
    int c = (g >> 6) & 255;
    int b = g >> 14;
    size_t base = (size_t)(b * 256 + c) * 4096 + w;
    float u  = first[c];
    float wn = -expf(decay[c]);
    float a = 0.f, bb = 0.f, pp = -1e38f;
    for (int h = 0; h < 64; ++h) {
        size_t idx = base + h * 64;
        float kt = kin[idx], vt = vin[idx];
        float q  = fmaxf(pp, u + kt);
        float e1 = expf(pp - q), e2 = expf(u + kt - q);
        float ov = (e1 * a + e2 * vt) / (e1 * bb + e2);
        outw[idx] = 0.5f * (outw[idx] + ov);
        float q2 = fmaxf(pp + wn, kt);
        float f1 = expf(pp + wn - q2), f2 = expf(kt - q2);
        a = f1 * a + f2 * vt;
        bb = f1 * bb + f2;
        pp = q2;
    }
}

// ---------------------------------------------------------------------------
extern "C" void kernel_launch(void* const* d_in, const int* in_sizes, int n_in,
                              void* d_out, int out_size, void* d_ws, size_t ws_size,
                              hipStream_t stream)
{
    const float* x      = (const float*)d_in[0];
    const float* skip   = (const float*)d_in[1];
    const float* mask   = (const float*)d_in[2];
    const float* ln1_w  = (const float*)d_in[3];
    const float* ln1_b  = (const float*)d_in[4];
    const float* ln2_w  = (const float*)d_in[5];
    const float* ln2_b  = (const float*)d_in[6];
    const float* mix_k  = (const float*)d_in[7];
    const float* mix_v  = (const float*)d_in[8];
    const float* mix_r  = (const float*)d_in[9];
    const float* Wk     = (const float*)d_in[10];
    const float* Wv     = (const float*)d_in[11];
    const float* Wr     = (const float*)d_in[12];
    const float* Wo     = (const float*)d_in[13];
    const float* decay  = (const float*)d_in[14];
    const float* first  = (const float*)d_in[15];
    const float* kn_w   = (const float*)d_in[16];
    const float* kn_b   = (const float*)d_in[17];
    const float* sp_w   = (const float*)d_in[18];
    const float* sp_b   = (const float*)d_in[19];
    const float* c1_w   = (const float*)d_in[20];
    const float* c1_b   = (const float*)d_in[21];
    const float* bn1_g  = (const float*)d_in[22];
    const float* bn1_b  = (const float*)d_in[23];
    const float* c2_w   = (const float*)d_in[24];
    const float* c2_b   = (const float*)d_in[25];
    const float* bn2_g  = (const float*)d_in[26];
    const float* bn2_b  = (const float*)d_in[27];
    const float* c3_w   = (const float*)d_in[28];
    const float* c3_b   = (const float*)d_in[29];
    const float* bn3_g  = (const float*)d_in[30];
    const float* bn3_b  = (const float*)d_in[31];
    const float* up_w   = (const float*)d_in[32];
    const float* up_b   = (const float*)d_in[33];
    float* out = (float*)d_out;

    float* ws = (float*)d_ws;
    const size_t S = 8388608;   // 8 Mi floats = 32 MiB
    // Arena (float units). Lifetimes:
    bf16_t* xk   = (bf16_t*)ws;                     // [0, S/2)       until k-GEMM
    bf16_t* xv   = (bf16_t*)(ws + S / 2);           // [S/2, S)       until v-GEMM
    bf16_t* xr   = (bf16_t*)(ws + S);               // [S, 3S/2)      until r-GEMM
    float*  kbuf = ws + 3 * S / 2;                  // [1.5S, 2.5S)   until scans
    float*  vbuf = ws + 5 * S / 2;                  // [2.5S, 3.5S)   until scans
    float*  rbuf = ws + 7 * S / 2;                  // [3.5S, 4.5S)   until Wo
    float*  wkv  = ws;                              // [0, S)         reuse xk+xv
    bf16_t* xcat = (bf16_t*)(ws + 3 * S / 2);       // [1.5S, 2.5S)   reuse kbuf
    bf16_t* y1   = (bf16_t*)(ws + 5 * S / 2);       // [2.5S, 3.5S)   reuse vbuf
    bf16_t* y2   = (bf16_t*)ws;                     // [0, 2S)        reuse wkv/xr+
    float*  y3   = ws + 2 * S;                      // [2S, 3S)       reuse xcat tail
    float*  wtop = ws + 9 * S / 2;
    bf16_t* w9   = (bf16_t*)wtop;                   // 1,179,648 bf16
    bf16_t* wfl  = w9 + 1179648;                    // 1,310,720 bf16
    float2* st1  = (float2*)(wfl + 1310720);        // 32768 float2
    float2* stk  = st1 + 32768;
    float2* st2  = stk + 32768;
    bf16_t* wkb = wfl;
    bf16_t* wvb = wfl + 65536;
    bf16_t* wrb = wfl + 131072;
    bf16_t* wob = wfl + 196608;
    bf16_t* spb = wfl + 262144;
    bf16_t* c2b = wfl + 393216;
    bf16_t* c3b = wfl + 917504;
    bf16_t* upb = wfl + 1179648;

    dim3 blk(256);

    // 0) weight packing + LN1 stats
    pack_weights<<<dim3(5120), blk, 0, stream>>>(Wk, Wv, Wr, Wo, sp_w, c2_w, c3_w, up_w, wfl);
    repack_conv_w<<<dim3(4608), blk, 0, stream>>>(c1_w, w9);
    ln_stats_kernel<<<dim3(512), blk, 0, stream>>>(x, st1);

    // 1) fused LN1 + q_shift + blend + mix -> xk/xv/xr (bf16)
    qshift_mix_kernel<<<dim3(32768), blk, 0, stream>>>(x, st1, mask, ln1_w, ln1_b,
                                                       mix_k, mix_v, mix_r, xk, xv, xr);
    // 2) k, v, sr
    mfma_gemm<1, 0, EP_NONE, 0><<<dim3(64, 2, 8), blk, 0, stream>>>(
        wkb, xk, nullptr, nullptr, nullptr, nullptr, nullptr, nullptr, nullptr,
        nullptr, nullptr, nullptr, nullptr, kbuf, 256, 256, 256, 256, 0);
    mfma_gemm<1, 0, EP_NONE, 0><<<dim3(64, 2, 8), blk, 0, stream>>>(
        wvb, xv, nullptr, nullptr, nullptr, nullptr, nullptr, nullptr, nullptr,
        nullptr, nullptr, nullptr, nullptr, vbuf, 256, 256, 256, 256, 0);
    mfma_gemm<1, 0, EP_SIGMOID, 0><<<dim3(64, 2, 8), blk, 0, stream>>>(
        wrb, xr, nullptr, nullptr, nullptr, nullptr, nullptr, nullptr, nullptr,
        nullptr, nullptr, nullptr, nullptr, rbuf, 256, 256, 256, 256, 0);
    // 3) WKV scans (h writes, v merges 0.5*(h+v))
    wkv_h_kernel<<<dim3(4, 64, 8), dim3(64), 0, stream>>>(kbuf, vbuf, wkv, decay, first);
    wkv_v_kernel<<<dim3(512), blk, 0, stream>>>(kbuf, vbuf, wkv, decay, first);
    // 4) kn-LN stats over wkv
    ln_stats_kernel<<<dim3(512), blk, 0, stream>>>(wkv, stk);
    // 5) x_sg = LN1(x) + Wo.(sr * LNkn(wkv)) -> xcat[:,0:256]
    mfma_gemm<1, 3, EP_RESLN, 1><<<dim3(64, 2, 8), blk, 0, stream>>>(
        wob, wkv, rbuf, stk, kn_w, kn_b, nullptr, nullptr, nullptr,
        x, st1, ln1_w, ln1_b, xcat, 256, 256, 256, 512, 0);
    // 6) skip_feat -> xcat[:,256:512]
    mfma_gemm<1, 1, EP_BIAS, 1><<<dim3(64, 2, 8), blk, 0, stream>>>(
        spb, skip, nullptr, nullptr, nullptr, nullptr, sp_b, nullptr, nullptr,
        nullptr, nullptr, nullptr, nullptr, xcat, 256, 512, 512, 512, 256);
    // 7) grouped 3x3 conv + gelu + bn1 -> y1
    mfma_gemm<3, 0, EP_GELU_BN, 1><<<dim3(64, 4, 8), blk, 0, stream>>>(
        w9, xcat, nullptr, nullptr, nullptr, nullptr, c1_b, bn1_g, bn1_b,
        nullptr, nullptr, nullptr, nullptr, y1, 512, 256, 512, 512, 0);
    // 8) c2 + gelu + bn2 -> y2
    mfma_gemm<1, 0, EP_GELU_BN, 1><<<dim3(64, 8, 8), blk, 0, stream>>>(
        c2b, y1, nullptr, nullptr, nullptr, nullptr, c2_b, bn2_g, bn2_b,
        nullptr, nullptr, nullptr, nullptr, y2, 1024, 512, 512, 1024, 0);
    // 9) c3 + gelu + bn3 -> y3 (fp32)
    mfma_gemm<1, 0, EP_GELU_BN, 0><<<dim3(64, 2, 8), blk, 0, stream>>>(
        c3b, y2, nullptr, nullptr, nullptr, nullptr, c3_b, bn3_g, bn3_b,
        nullptr, nullptr, nullptr, nullptr, y3, 256, 1024, 1024, 256, 0);
    // 10) LN2 stats over y3
    ln_stats_kernel<<<dim3(512), blk, 0, stream>>>(y3, st2);
    // 11) up-projection (LN2 folded into B-stage) + pixel shuffle -> out
    mfma_gemm<1, 2, EP_SHUFFLE, 0><<<dim3(64, 4, 8), blk, 0, stream>>>(
        upb, y3, nullptr, st2, ln2_w, ln2_b, up_b, nullptr, nullptr,
        nullptr, nullptr, nullptr, nullptr, out, 512, 256, 256, 0, 0);
}

// Round 5
// 506.651 us; speedup vs baseline: 9.9981x; 1.0418x over previous
//
#include <hip/hip_runtime.h>
#include <hip/hip_bf16.h>
#include <math.h>

#define B_ 8
#define C_ 256
#define P_ 4096

typedef __bf16 bf16_t;
typedef __attribute__((ext_vector_type(8))) __bf16 bf16x8;
typedef __attribute__((ext_vector_type(4))) float f32x4;

// ---------------------------------------------------------------------------
// Channel-LN stats: per (b,p) mean and rstd over C=256.
// ---------------------------------------------------------------------------
__global__ __launch_bounds__(256)
void ln_stats_kernel(const float* __restrict__ in, float2* __restrict__ stats)
{
    __shared__ float sred[4][64];
    __shared__ float s2red[4][64];
    int tid = threadIdx.x;
    int wp = tid & 63, cw = tid >> 6;
    int gp = blockIdx.x * 64 + wp;
    int b  = gp >> 12, p = gp & 4095;
    size_t base = (size_t)b * 256 * 4096 + p;
    float s = 0.f, s2 = 0.f;
    #pragma unroll 8
    for (int cc = 0; cc < 64; ++cc) {
        float v = in[base + (size_t)(cw * 64 + cc) * 4096];
        s += v; s2 += v * v;
    }
    sred[cw][wp] = s; s2red[cw][wp] = s2;
    __syncthreads();
    if (cw == 0) {
        s  = sred[0][wp]  + sred[1][wp]  + sred[2][wp]  + sred[3][wp];
        s2 = s2red[0][wp] + s2red[1][wp] + s2red[2][wp] + s2red[3][wp];
        float mu  = s * (1.f / 256.f);
        float var = s2 * (1.f / 256.f) - mu * mu;
        stats[gp] = make_float2(mu, 1.0f / sqrtf(var + 1e-5f));
    }
}

// ---------------------------------------------------------------------------
// Fused: LN1(on-the-fly) + q_shift + saliency blend + 3-way token-mix -> bf16
// ---------------------------------------------------------------------------
__global__ __launch_bounds__(256)
void qshift_mix_kernel(const float* __restrict__ x, const float2* __restrict__ st1,
                       const float* __restrict__ mask,
                       const float* __restrict__ gw, const float* __restrict__ gb,
                       const float* __restrict__ mk_, const float* __restrict__ mv_,
                       const float* __restrict__ mr_,
                       bf16_t* __restrict__ xk, bf16_t* __restrict__ xv,
                       bf16_t* __restrict__ xr)
{
    int g = blockIdx.x * 256 + threadIdx.x;
    int p = g & 4095;
    int c = (g >> 12) & 255;
    int b = g >> 20;
    int h = p >> 6, w = p & 63;
    float gwc = gw[c], gbc = gb[c];
    float2 stc = st1[(b << 12) + p];
    float xcv = (x[g] - stc.x) * stc.y * gwc + gbc;
    float xs = 0.f;
    int quad = c >> 6;
    int d = 0; bool ok = false;
    if (quad == 0)      { ok = (w > 0);  d = -1;  }
    else if (quad == 1) { ok = (w < 63); d = 1;   }
    else if (quad == 2) { ok = (h > 0);  d = -64; }
    else                { ok = (h < 63); d = 64;  }
    if (ok) {
        float2 st2 = st1[(b << 12) + p + d];
        xs = (x[g + d] - st2.x) * st2.y * gwc + gbc;
    }
    float m = mask[(b << 12) + p];
    float xsh = m * xs + (1.f - m) * xcv;
    float a;
    a = mk_[c]; xk[g] = (bf16_t)(a * xcv + (1.f - a) * xsh);
    a = mv_[c]; xv[g] = (bf16_t)(a * xcv + (1.f - a) * xsh);
    a = mr_[c]; xr[g] = (bf16_t)(a * xcv + (1.f - a) * xsh);
}

// ---------------------------------------------------------------------------
// 128x128-tile bf16 MFMA implicit GEMM. 4 waves (2x2), each 64x64 (4m x 4n).
//   NB: 3 = grouped 3x3 conv (W packed [9][O][256], p-tile = 2 h rows);
//       1 = 1x1 (W [O][K])
//   BMODE: 0 bf16 | 1 f32 | 2 f32 LN | 3 X2 * (f32 LN)
//   EPI: 0 none | 1 sigmoid | 2 +bias | 3 +LN(resx) | 4 gelu+bn | 5 shuffle
// LDS rows padded to 36 elems (72 B = 18-bank stride -> ~2-way, free).
// ---------------------------------------------------------------------------
#define EP_NONE    0
#define EP_SIGMOID 1
#define EP_BIAS    2
#define EP_RESLN   3
#define EP_GELU_BN 4
#define EP_SHUFFLE 5

template<int NB, int BMODE, int EPI, int OUTBF>
__global__ __launch_bounds__(256, 2)
void mfma_gemm(const bf16_t* __restrict__ Wp, const void* __restrict__ Xin,
               const float* __restrict__ X2,
               const float2* __restrict__ bstats, const float* __restrict__ blnw,
               const float* __restrict__ blnb,
               const float* __restrict__ bias, const float* __restrict__ bng,
               const float* __restrict__ bnb,
               const float* __restrict__ resx, const float2* __restrict__ estats,
               const float* __restrict__ elnw, const float* __restrict__ elnb,
               void* __restrict__ OutV,
               int O, int K, int Cstride, int obs, int ocoff)
{
    constexpr int BROWS = (NB == 3) ? 2 * 66 : 128;
    __shared__ bf16_t Alds[NB * 128 * 36];
    __shared__ bf16_t Blds[BROWS * 36];
    int tid = threadIdx.x;
    int bx = blockIdx.x;
    int o0 = blockIdx.y * 128;
    int b  = blockIdx.z;
    int p0 = bx << 7;
    int cbase = (NB == 3) ? ((o0 >> 8) << 8) : 0;

    int lane = tid & 63, wid = tid >> 6;
    int l15 = lane & 15;
    int lk8 = (lane >> 4) << 3;
    int mbase = (wid >> 1) << 6;
    int nbase = (wid & 1) << 6;

    const bf16_t* Xb_bf = (const bf16_t*)Xin + (size_t)b * Cstride * 4096;
    const float*  Xb_f  = (const float*)Xin + (size_t)b * Cstride * 4096;
    const float*  X2b   = (BMODE == 3) ? X2 + (size_t)b * Cstride * 4096 : nullptr;

    f32x4 acc[4][4] = {};

    // zero the always-padding halo columns (wloc 0 and 65) once
    if (NB == 3 && tid < 144) {
        int r = tid / 72, rest = tid % 72;
        int col = rest / 36, cc = rest % 36;
        Blds[(r * 66 + (col ? 65 : 0)) * 36 + cc] = (bf16_t)0.f;
    }

    for (int kh = 0; kh < NB; ++kh) {
        for (int c0 = 0; c0 < K; c0 += 32) {
            __syncthreads();
            // ---- stage B ----
            if (NB == 3) {
                int wpos = tid & 63, cgr = tid >> 6;
                #pragma unroll
                for (int r = 0; r < 2; ++r) {
                    int hr = (bx << 1) + kh - 1 + r;
                    bf16x8 bv;
                    #pragma unroll
                    for (int i = 0; i < 8; ++i) bv[i] = (bf16_t)0.f;
                    if (hr >= 0 && hr < 64) {
                        size_t gb = (size_t)(cbase + c0 + cgr * 8) * 4096 + (hr << 6) + wpos;
                        #pragma unroll
                        for (int j = 0; j < 8; ++j) bv[j] = Xb_bf[gb + (size_t)j * 4096];
                    }
                    *reinterpret_cast<bf16x8*>(&Blds[(r * 66 + wpos + 1) * 36 + cgr * 8]) = bv;
                }
            } else {
                #pragma unroll
                for (int rep = 0; rep < 2; ++rep) {
                    int p_loc = tid & 127;
                    int cgr = (tid >> 7) + rep * 2;
                    bf16x8 bv;
                    size_t gbase = (size_t)(c0 + cgr * 8) * 4096 + p0 + p_loc;
                    float2 st = make_float2(0.f, 1.f);
                    if (BMODE >= 2) st = bstats[(b << 12) + p0 + p_loc];
                    #pragma unroll
                    for (int j = 0; j < 8; ++j) {
                        size_t gi = gbase + (size_t)j * 4096;
                        int cc = c0 + cgr * 8 + j;
                        if (BMODE == 0)      bv[j] = Xb_bf[gi];
                        else if (BMODE == 1) bv[j] = (bf16_t)Xb_f[gi];
                        else {
                            float v = (Xb_f[gi] - st.x) * st.y * blnw[cc] + blnb[cc];
                            if (BMODE == 3) v *= X2b[gi];
                            bv[j] = (bf16_t)v;
                        }
                    }
                    *reinterpret_cast<bf16x8*>(&Blds[p_loc * 36 + cgr * 8]) = bv;
                }
            }
            // ---- stage A ----
            {
                int ao = tid >> 1, aq = tid & 1;
                #pragma unroll
                for (int t = 0; t < NB; ++t) {
                    const bf16_t* wsrc = (NB == 3)
                        ? Wp + ((size_t)(kh * 3 + t) * O + o0 + ao) * 256 + c0
                        : Wp + (size_t)(o0 + ao) * K + c0;
                    bf16x8 w0 = *reinterpret_cast<const bf16x8*>(wsrc + aq * 8);
                    bf16x8 w1 = *reinterpret_cast<const bf16x8*>(wsrc + (aq + 2) * 8);
                    *reinterpret_cast<bf16x8*>(&Alds[(t * 128 + ao) * 36 + aq * 8]) = w0;
                    *reinterpret_cast<bf16x8*>(&Alds[(t * 128 + ao) * 36 + (aq + 2) * 8]) = w1;
                }
            }
            __syncthreads();
            // ---- MFMA ----
            #pragma unroll
            for (int t = 0; t < NB; ++t) {
                bf16x8 af[4];
                #pragma unroll
                for (int i = 0; i < 4; ++i)
                    af[i] = *reinterpret_cast<const bf16x8*>(
                              &Alds[(t * 128 + mbase + i * 16 + l15) * 36 + lk8]);
                #pragma unroll
                for (int j = 0; j < 4; ++j) {
                    int pl = nbase + j * 16;
                    int baddr;
                    if (NB == 3)
                        baddr = ((pl >> 6) * 66 + (pl & 63) + l15 + t) * 36 + lk8;
                    else
                        baddr = (pl + l15) * 36 + lk8;
                    bf16x8 bfv = *reinterpret_cast<const bf16x8*>(&Blds[baddr]);
                    #pragma unroll
                    for (int i = 0; i < 4; ++i)
                        acc[i][j] = __builtin_amdgcn_mfma_f32_16x16x32_bf16(
                                        af[i], bfv, acc[i][j], 0, 0, 0);
                }
            }
        }
    }

    const float bnsc = 1.0f / sqrtf(1.f + 1e-5f);
    #pragma unroll
    for (int i = 0; i < 4; ++i) {
        #pragma unroll
        for (int r = 0; r < 4; ++r) {
            int o = o0 + mbase + i * 16 + ((lane >> 4) << 2) + r;
            float bi = (EPI == EP_BIAS || EPI == EP_GELU_BN || EPI == EP_SHUFFLE)
                       ? bias[o] : 0.f;
            float sc = 0.f, sh = 0.f;
            if (EPI == EP_GELU_BN) { sc = bng[o] * bnsc; sh = bnb[o]; }
            float rw = 0.f, rb = 0.f;
            if (EPI == EP_RESLN) { rw = elnw[o]; rb = elnb[o]; }
            #pragma unroll
            for (int j = 0; j < 4; ++j) {
                int pp = p0 + nbase + j * 16 + l15;
                float t = acc[i][j][r];
                if (EPI == EP_SIGMOID) t = 1.f / (1.f + expf(-t));
                if (EPI == EP_BIAS || EPI == EP_GELU_BN || EPI == EP_SHUFFLE) t += bi;
                if (EPI == EP_RESLN) {
                    float2 st = estats[(b << 12) + pp];
                    float rv = resx[((size_t)b * 256 + o) * 4096 + pp];
                    t += (rv - st.x) * st.y * rw + rb;
                }
                if (EPI == EP_GELU_BN) {
                    t = 0.5f * t * (1.f + erff(t * 0.70710678118654752f));
                    t = t * sc + sh;
                }
                if (EPI == EP_SHUFFLE) {
                    int co = o >> 2, s1 = (o >> 1) & 1, s2 = o & 1;
                    int hh = pp >> 6, ww = pp & 63;
                    ((float*)OutV)[(((size_t)b * 128 + co) * 128 + hh * 2 + s1) * 128
                                   + ww * 2 + s2] = t;
                } else {
                    size_t oidx = ((size_t)b * obs + ocoff + o) * 4096 + pp;
                    if (OUTBF) ((bf16_t*)OutV)[oidx] = (bf16_t)t;
                    else       ((float*)OutV)[oidx]  = t;
                }
            }
        }
    }
}

// ---------------------------------------------------------------------------
// Weight packing
// ---------------------------------------------------------------------------
__global__ __launch_bounds__(256)
void repack_conv_w(const float* __restrict__ w, bf16_t* __restrict__ out)
{
    int g = blockIdx.x * 256 + threadIdx.x;
    int c = g & 255;
    int o = (g >> 8) & 511;
    int tap = g >> 17;
    out[g] = (bf16_t)w[(size_t)o * 2304 + c * 9 + tap];
}

__global__ __launch_bounds__(256)
void pack_weights(const float* __restrict__ wk, const float* __restrict__ wv,
                  const float* __restrict__ wr, const float* __restrict__ wo,
                  const float* __restrict__ sp, const float* __restrict__ c2,
                  const float* __restrict__ c3, const float* __restrict__ up,
                  bf16_t* __restrict__ out)
{
    int g = blockIdx.x * 256 + threadIdx.x;
    float v;
    if      (g < 65536)   v = wk[g];
    else if (g < 131072)  v = wv[g - 65536];
    else if (g < 196608)  v = wr[g - 131072];
    else if (g < 262144)  v = wo[g - 196608];
    else if (g < 393216)  v = sp[g - 262144];
    else if (g < 917504)  v = c2[g - 393216];
    else if (g < 1179648) v = c3[g - 917504];
    else                  v = up[g - 1179648];
    out[g] = (bf16_t)v;
}

// ---------------------------------------------------------------------------
// WKV scans
// ---------------------------------------------------------------------------
__global__ __launch_bounds__(64)
void wkv_h_kernel(const float* __restrict__ kin, const float* __restrict__ vin,
                  float* __restrict__ outw,
                  const float* __restrict__ decay, const float* __restrict__ first)
{
    __shared__ float ks[64][65];
    __shared__ float vs[64][65];
    int c0 = blockIdx.x * 64;
    int h  = blockIdx.y;
    int b  = blockIdx.z;
    int tid = threadIdx.x;
    size_t base = (((size_t)b * 256 + c0) * 64 + h) * 64;

    for (int f = tid; f < 64 * 64; f += 64) {
        int cc = f >> 6, w = f & 63;
        ks[cc][w] = kin[base + (size_t)cc * 4096 + w];
        vs[cc][w] = vin[base + (size_t)cc * 4096 + w];
    }
    __syncthreads();

    int c = c0 + tid;
    float u  = first[c];
    float wn = -expf(decay[c]);
    float a = 0.f, bb = 0.f, pp = -1e38f;
    for (int t = 0; t < 64; ++t) {
        float kt = ks[tid][t], vt = vs[tid][t];
        float q  = fmaxf(pp, u + kt);
        float e1 = expf(pp - q), e2 = expf(u + kt - q);
        float ov = (e1 * a + e2 * vt) / (e1 * bb + e2);
        ks[tid][t] = ov;
        float q2 = fmaxf(pp + wn, kt);
        float f1 = expf(pp + wn - q2), f2 = expf(kt - q2);
        a = f1 * a + f2 * vt;
        bb = f1 * bb + f2;
        pp = q2;
    }
    __syncthreads();
    for (int f = tid; f < 64 * 64; f += 64) {
        int cc = f >> 6, w = f & 63;
        outw[base + (size_t)cc * 4096 + w] = ks[cc][w];
    }
}

__global__ __launch_bounds__(256)
void wkv_v_kernel(const float* __restrict__ kin, const float* __restrict__ vin,
                  float* __restrict__ outw,
                  const float* __restrict__ decay, const float* __restrict__ first)
{
    int g = blockIdx.x * 256 + threadIdx.x;
    int w = g & 63;
    int c = (g >> 6) & 255;
    int b = g >> 14;
    size_t base = (size_t)(b * 256 + c) * 4096 + w;
    float u  = first[c];
    float wn = -expf(decay[c]);
    float a = 0.f, bb = 0.f, pp = -1e38f;
    for (int h = 0; h < 64; ++h) {
        size_t idx = base + h * 64;
        float kt = kin[idx], vt = vin[idx];
        float q  = fmaxf(pp, u + kt);
        float e1 = expf(pp - q), e2 = expf(u + kt - q);
        float ov = (e1 * a + e2 * vt) / (e1 * bb + e2);
        outw[idx] = 0.5f * (outw[idx] + ov);
        float q2 = fmaxf(pp + wn, kt);
        float f1 = expf(pp + wn - q2), f2 = expf(kt - q2);
        a = f1 * a + f2 * vt;
        bb = f1 * bb + f2;
        pp = q2;
    }
}

// ---------------------------------------------------------------------------
extern "C" void kernel_launch(void* const* d_in, const int* in_sizes, int n_in,
                              void* d_out, int out_size, void* d_ws, size_t ws_size,
                              hipStream_t stream)
{
    const float* x      = (const float*)d_in[0];
    const float* skip   = (const float*)d_in[1];
    const float* mask   = (const float*)d_in[2];
    const float* ln1_w  = (const float*)d_in[3];
    const float* ln1_b  = (const float*)d_in[4];
    const float* ln2_w  = (const float*)d_in[5];
    const float* ln2_b  = (const float*)d_in[6];
    const float* mix_k  = (const float*)d_in[7];
    const float* mix_v  = (const float*)d_in[8];
    const float* mix_r  = (const float*)d_in[9];
    const float* Wk     = (const float*)d_in[10];
    const float* Wv     = (const float*)d_in[11];
    const float* Wr     = (const float*)d_in[12];
    const float* Wo     = (const float*)d_in[13];
    const float* decay  = (const float*)d_in[14];
    const float* first  = (const float*)d_in[15];
    const float* kn_w   = (const float*)d_in[16];
    const float* kn_b   = (const float*)d_in[17];
    const float* sp_w   = (const float*)d_in[18];
    const float* sp_b   = (const float*)d_in[19];
    const float* c1_w   = (const float*)d_in[20];
    const float* c1_b   = (const float*)d_in[21];
    const float* bn1_g  = (const float*)d_in[22];
    const float* bn1_b  = (const float*)d_in[23];
    const float* c2_w   = (const float*)d_in[24];
    const float* c2_b   = (const float*)d_in[25];
    const float* bn2_g  = (const float*)d_in[26];
    const float* bn2_b  = (const float*)d_in[27];
    const float* c3_w   = (const float*)d_in[28];
    const float* c3_b   = (const float*)d_in[29];
    const float* bn3_g  = (const float*)d_in[30];
    const float* bn3_b  = (const float*)d_in[31];
    const float* up_w   = (const float*)d_in[32];
    const float* up_b   = (const float*)d_in[33];
    float* out = (float*)d_out;

    float* ws = (float*)d_ws;
    const size_t S = 8388608;   // 8 Mi floats = 32 MiB
    bf16_t* xk   = (bf16_t*)ws;                     // [0, S/2)
    bf16_t* xv   = (bf16_t*)(ws + S / 2);           // [S/2, S)
    bf16_t* xr   = (bf16_t*)(ws + S);               // [S, 3S/2)
    float*  kbuf = ws + 3 * S / 2;                  // [1.5S, 2.5S)
    float*  vbuf = ws + 5 * S / 2;                  // [2.5S, 3.5S)
    float*  rbuf = ws + 7 * S / 2;                  // [3.5S, 4.5S)
    float*  wkv  = ws;                              // [0, S) reuse xk+xv
    bf16_t* xcat = (bf16_t*)(ws + 3 * S / 2);       // [1.5S, 2.5S) reuse kbuf
    bf16_t* y1   = (bf16_t*)(ws + 5 * S / 2);       // [2.5S, 3.5S) reuse vbuf
    bf16_t* y2   = (bf16_t*)ws;                     // [0, 2S) reuse wkv/xr
    float*  y3   = ws + 2 * S;                      // [2S, 3S)
    float*  wtop = ws + 9 * S / 2;
    bf16_t* w9   = (bf16_t*)wtop;
    bf16_t* wfl  = w9 + 1179648;
    float2* st1  = (float2*)(wfl + 1310720);
    float2* stk  = st1 + 32768;
    float2* st2  = stk + 32768;
    bf16_t* wkb = wfl;
    bf16_t* wvb = wfl + 65536;
    bf16_t* wrb = wfl + 131072;
    bf16_t* wob = wfl + 196608;
    bf16_t* spb = wfl + 262144;
    bf16_t* c2b = wfl + 393216;
    bf16_t* c3b = wfl + 917504;
    bf16_t* upb = wfl + 1179648;

    dim3 blk(256);

    pack_weights<<<dim3(5120), blk, 0, stream>>>(Wk, Wv, Wr, Wo, sp_w, c2_w, c3_w, up_w, wfl);
    repack_conv_w<<<dim3(4608), blk, 0, stream>>>(c1_w, w9);
    ln_stats_kernel<<<dim3(512), blk, 0, stream>>>(x, st1);

    qshift_mix_kernel<<<dim3(32768), blk, 0, stream>>>(x, st1, mask, ln1_w, ln1_b,
                                                       mix_k, mix_v, mix_r, xk, xv, xr);
    // k, v, sr
    mfma_gemm<1, 0, EP_NONE, 0><<<dim3(32, 2, 8), blk, 0, stream>>>(
        wkb, xk, nullptr, nullptr, nullptr, nullptr, nullptr, nullptr, nullptr,
        nullptr, nullptr, nullptr, nullptr, kbuf, 256, 256, 256, 256, 0);
    mfma_gemm<1, 0, EP_NONE, 0><<<dim3(32, 2, 8), blk, 0, stream>>>(
        wvb, xv, nullptr, nullptr, nullptr, nullptr, nullptr, nullptr, nullptr,
        nullptr, nullptr, nullptr, nullptr, vbuf, 256, 256, 256, 256, 0);
    mfma_gemm<1, 0, EP_SIGMOID, 0><<<dim3(32, 2, 8), blk, 0, stream>>>(
        wrb, xr, nullptr, nullptr, nullptr, nullptr, nullptr, nullptr, nullptr,
        nullptr, nullptr, nullptr, nullptr, rbuf, 256, 256, 256, 256, 0);
    // WKV scans
    wkv_h_kernel<<<dim3(4, 64, 8), dim3(64), 0, stream>>>(kbuf, vbuf, wkv, decay, first);
    wkv_v_kernel<<<dim3(512), blk, 0, stream>>>(kbuf, vbuf, wkv, decay, first);
    ln_stats_kernel<<<dim3(512), blk, 0, stream>>>(wkv, stk);
    // x_sg = LN1(x) + Wo.(sr * LNkn(wkv)) -> xcat[:,0:256]
    mfma_gemm<1, 3, EP_RESLN, 1><<<dim3(32, 2, 8), blk, 0, stream>>>(
        wob, wkv, rbuf, stk, kn_w, kn_b, nullptr, nullptr, nullptr,
        x, st1, ln1_w, ln1_b, xcat, 256, 256, 256, 512, 0);
    // skip_feat -> xcat[:,256:512]
    mfma_gemm<1, 1, EP_BIAS, 1><<<dim3(32, 2, 8), blk, 0, stream>>>(
        spb, skip, nullptr, nullptr, nullptr, nullptr, sp_b, nullptr, nullptr,
        nullptr, nullptr, nullptr, nullptr, xcat, 256, 512, 512, 512, 256);
    // grouped 3x3 conv + gelu + bn1 -> y1
    mfma_gemm<3, 0, EP_GELU_BN, 1><<<dim3(32, 4, 8), blk, 0, stream>>>(
        w9, xcat, nullptr, nullptr, nullptr, nullptr, c1_b, bn1_g, bn1_b,
        nullptr, nullptr, nullptr, nullptr, y1, 512, 256, 512, 512, 0);
    // c2 + gelu + bn2 -> y2
    mfma_gemm<1, 0, EP_GELU_BN, 1><<<dim3(32, 8, 8), blk, 0, stream>>>(
        c2b, y1, nullptr, nullptr, nullptr, nullptr, c2_b, bn2_g, bn2_b,
        nullptr, nullptr, nullptr, nullptr, y2, 1024, 512, 512, 1024, 0);
    // c3 + gelu + bn3 -> y3 (fp32)
    mfma_gemm<1, 0, EP_GELU_BN, 0><<<dim3(32, 2, 8), blk, 0, stream>>>(
        c3b, y2, nullptr, nullptr, nullptr, nullptr, c3_b, bn3_g, bn3_b,
        nullptr, nullptr, nullptr, nullptr, y3, 256, 1024, 1024, 256, 0);
    ln_stats_kernel<<<dim3(512), blk, 0, stream>>>(y3, st2);
    // up-projection (LN2 folded) + pixel shuffle -> out
    mfma_gemm<1, 2, EP_SHUFFLE, 0><<<dim3(32, 4, 8), blk, 0, stream>>>(
        upb, y3, nullptr, st2, ln2_w, ln2_b, up_b, nullptr, nullptr,
        nullptr, nullptr, nullptr, nullptr, out, 512, 256, 256, 0, 0);
}